// Round 1
// baseline (3019.012 us; speedup 1.0000x reference)
//
#include <hip/hip_runtime.h>
#include <math.h>

#define B 8
#define C 64
#define NN 4096
#define O 64
#define KNN 20
#define NQ 2   // queries per block in knn kernel

// ---------------- K1: transpose x (B,C,N) -> xt (B,N,C), and xx = sum_c x^2 ----------------
__global__ __launch_bounds__(256) void k1_transpose(const float* __restrict__ x,
                                                    float* __restrict__ xt,
                                                    float* __restrict__ xx) {
    __shared__ float tile[64][65];
    int b  = blockIdx.x / (NN / 64);
    int n0 = (blockIdx.x % (NN / 64)) * 64;
    int t = threadIdx.x;
    #pragma unroll
    for (int it = 0; it < 16; ++it) {
        int i = it * 256 + t;
        int c = i >> 6, n = i & 63;
        tile[c][n] = x[(size_t)b * C * NN + (size_t)c * NN + n0 + n];
    }
    __syncthreads();
    #pragma unroll
    for (int it = 0; it < 16; ++it) {
        int i = it * 256 + t;
        int n = i >> 6, c = i & 63;
        xt[((size_t)(b * NN + n0 + n)) * C + c] = tile[c][n];
    }
    if (t < 64) {
        float s = 0.f;
        #pragma unroll
        for (int c = 0; c < 64; ++c) { float v = tile[c][t]; s = fmaf(v, v, s); }
        xx[(size_t)b * NN + n0 + t] = s;
    }
}

// ---------------- K2: KNN top-K per point ----------------
__global__ __launch_bounds__(256) void k2_knn(const float* __restrict__ xt,
                                              const float* __restrict__ xx,
                                              int* __restrict__ idx) {
    __shared__ float dist[NQ][NN];   // 32KB
    __shared__ float qv[NQ][64];
    int b  = blockIdx.x / (NN / NQ);
    int n0 = (blockIdx.x % (NN / NQ)) * NQ;
    int t = threadIdx.x;
    if (t < NQ * 64) {
        int q = t >> 6, c = t & 63;
        qv[q][c] = xt[((size_t)(b * NN + n0 + q)) * C + c];
    }
    __syncthreads();
    const float* xb  = xt + (size_t)b * NN * C;
    const float* xxb = xx + (size_t)b * NN;
    float qxx0 = xxb[n0], qxx1 = xxb[n0 + 1];
    const float4* qA = (const float4*)qv[0];
    const float4* qB = (const float4*)qv[1];
    for (int p = 0; p < 4; ++p) {
        int m0 = p * 1024 + t;
        const float4* r0 = (const float4*)(xb + (size_t)m0 * C);
        const float4* r1 = (const float4*)(xb + (size_t)(m0 + 256) * C);
        const float4* r2 = (const float4*)(xb + (size_t)(m0 + 512) * C);
        const float4* r3 = (const float4*)(xb + (size_t)(m0 + 768) * C);
        float a0 = 0, a1 = 0, a2 = 0, a3 = 0;
        float b0 = 0, b1 = 0, b2 = 0, b3 = 0;
        #pragma unroll
        for (int c4 = 0; c4 < 16; ++c4) {
            float4 qa = qA[c4], qb = qB[c4];
            float4 v0 = r0[c4], v1 = r1[c4], v2 = r2[c4], v3 = r3[c4];
            a0 = fmaf(qa.x, v0.x, a0); a0 = fmaf(qa.y, v0.y, a0); a0 = fmaf(qa.z, v0.z, a0); a0 = fmaf(qa.w, v0.w, a0);
            a1 = fmaf(qa.x, v1.x, a1); a1 = fmaf(qa.y, v1.y, a1); a1 = fmaf(qa.z, v1.z, a1); a1 = fmaf(qa.w, v1.w, a1);
            a2 = fmaf(qa.x, v2.x, a2); a2 = fmaf(qa.y, v2.y, a2); a2 = fmaf(qa.z, v2.z, a2); a2 = fmaf(qa.w, v2.w, a2);
            a3 = fmaf(qa.x, v3.x, a3); a3 = fmaf(qa.y, v3.y, a3); a3 = fmaf(qa.z, v3.z, a3); a3 = fmaf(qa.w, v3.w, a3);
            b0 = fmaf(qb.x, v0.x, b0); b0 = fmaf(qb.y, v0.y, b0); b0 = fmaf(qb.z, v0.z, b0); b0 = fmaf(qb.w, v0.w, b0);
            b1 = fmaf(qb.x, v1.x, b1); b1 = fmaf(qb.y, v1.y, b1); b1 = fmaf(qb.z, v1.z, b1); b1 = fmaf(qb.w, v1.w, b1);
            b2 = fmaf(qb.x, v2.x, b2); b2 = fmaf(qb.y, v2.y, b2); b2 = fmaf(qb.z, v2.z, b2); b2 = fmaf(qb.w, v2.w, b2);
            b3 = fmaf(qb.x, v3.x, b3); b3 = fmaf(qb.y, v3.y, b3); b3 = fmaf(qb.z, v3.z, b3); b3 = fmaf(qb.w, v3.w, b3);
        }
        float x0 = xxb[m0], x1 = xxb[m0 + 256], x2 = xxb[m0 + 512], x3 = xxb[m0 + 768];
        dist[0][m0]       = 2.f * a0 - qxx0 - x0;
        dist[0][m0 + 256] = 2.f * a1 - qxx0 - x1;
        dist[0][m0 + 512] = 2.f * a2 - qxx0 - x2;
        dist[0][m0 + 768] = 2.f * a3 - qxx0 - x3;
        dist[1][m0]       = 2.f * b0 - qxx1 - x0;
        dist[1][m0 + 256] = 2.f * b1 - qxx1 - x1;
        dist[1][m0 + 512] = 2.f * b2 - qxx1 - x2;
        dist[1][m0 + 768] = 2.f * b3 - qxx1 - x3;
    }
    __syncthreads();
    int w = t >> 6, lane = t & 63;
    if (w < NQ) {
        float* d = dist[w];
        float4* d4 = (float4*)d;
        size_t obase = ((size_t)(b * NN + n0 + w)) * KNN;
        for (int k = 0; k < KNN; ++k) {
            float bv = -INFINITY; int bi = 0x7fffffff;
            #pragma unroll
            for (int i = 0; i < 16; ++i) {
                int e4 = i * 64 + lane;
                float4 v = d4[e4];
                int m = e4 * 4;
                if (v.x > bv || (v.x == bv && m     < bi)) { bv = v.x; bi = m; }
                if (v.y > bv || (v.y == bv && m + 1 < bi)) { bv = v.y; bi = m + 1; }
                if (v.z > bv || (v.z == bv && m + 2 < bi)) { bv = v.z; bi = m + 2; }
                if (v.w > bv || (v.w == bv && m + 3 < bi)) { bv = v.w; bi = m + 3; }
            }
            #pragma unroll
            for (int off = 32; off; off >>= 1) {
                float ov = __shfl_xor(bv, off);
                int   oi = __shfl_xor(bi, off);
                if (ov > bv || (ov == bv && oi < bi)) { bv = ov; bi = oi; }
            }
            if (lane == 0) idx[obase + k] = bi;
            if (((bi >> 2) & 63) == lane) d[bi] = -INFINITY;
        }
    }
}

// ---------------- K3a: Z = xt @ W0^T, Z2 = xt @ (W1-W0)^T ----------------
__global__ __launch_bounds__(256) void k3a_gemm(const float* __restrict__ xt,
                                                const float* __restrict__ W,
                                                float* __restrict__ Z,
                                                float* __restrict__ Z2) {
    __shared__ float W0t[64][65];
    __shared__ float W21t[64][65];
    __shared__ float xs[16][64];
    int t = threadIdx.x;
    #pragma unroll
    for (int it = 0; it < 16; ++it) {
        int i = it * 256 + t;
        int o = i >> 6, c = i & 63;
        float w0 = W[o * 128 + c];
        float w1 = W[o * 128 + 64 + c];
        W0t[c][o]  = w0;
        W21t[c][o] = w1 - w0;
    }
    int b  = blockIdx.x / (NN / 16);
    int nb = (blockIdx.x % (NN / 16)) * 16;
    #pragma unroll
    for (int it = 0; it < 4; ++it) {
        int i = it * 256 + t;
        int r = i >> 6, c = i & 63;
        xs[r][c] = xt[((size_t)(b * NN + nb + r)) * C + c];
    }
    __syncthreads();
    int o = t & 63, rg = t >> 6;
    #pragma unroll
    for (int rr = 0; rr < 4; ++rr) {
        int r = rg * 4 + rr;
        float z = 0.f, z2 = 0.f;
        #pragma unroll
        for (int c = 0; c < 64; ++c) {
            float xv = xs[r][c];
            z  = fmaf(xv, W0t[c][o],  z);
            z2 = fmaf(xv, W21t[c][o], z2);
        }
        size_t off = ((size_t)(b * NN + nb + r)) * 64 + o;
        Z[off]  = z;
        Z2[off] = z2;
    }
}

// ---------------- K3b: gather neighbors, per-(b,n,o) max/min over k, block-partial sums ----------------
__global__ __launch_bounds__(256) void k3b_gather(const float* __restrict__ Z,
                                                  const float* __restrict__ Z2,
                                                  const int* __restrict__ idx,
                                                  float* __restrict__ maxY,
                                                  float* __restrict__ minY,
                                                  float* __restrict__ partials) {
    int t = threadIdx.x;
    int p = t >> 6, o = t & 63;
    int b = blockIdx.x / (NN / 4);
    int n = (blockIdx.x % (NN / 4)) * 4 + p;
    size_t base = (size_t)(b * NN + n);
    float z2 = Z2[base * 64 + o];
    __shared__ int sidx[4][KNN];
    if (o < KNN) sidx[p][o] = idx[base * KNN + o];
    __syncthreads();
    const float* Zb = Z + (size_t)b * NN * 64;
    float s1 = 0.f, s2 = 0.f, mx = -INFINITY, mn = INFINITY;
    #pragma unroll
    for (int k = 0; k < KNN; ++k) {
        float y = Zb[(size_t)sidx[p][k] * 64 + o] + z2;
        s1 += y;
        s2 = fmaf(y, y, s2);
        mx = fmaxf(mx, y);
        mn = fminf(mn, y);
    }
    maxY[base * 64 + o] = mx;
    minY[base * 64 + o] = mn;
    __shared__ float red[2][4][64];
    red[0][p][o] = s1;
    red[1][p][o] = s2;
    __syncthreads();
    if (t < 64) {
        float a = red[0][0][t] + red[0][1][t] + red[0][2][t] + red[0][3][t];
        float c = red[1][0][t] + red[1][1][t] + red[1][2][t] + red[1][3][t];
        partials[(size_t)blockIdx.x * 128 + t]      = a;
        partials[(size_t)blockIdx.x * 128 + 64 + t] = c;
    }
}

// ---------------- K4a: reduce 8192 partial rows -> 64 rows ----------------
__global__ __launch_bounds__(256) void k4a_reduce(const float* __restrict__ partials,
                                                  float* __restrict__ partials2) {
    int g = blockIdx.x;          // 0..63
    int t = threadIdx.x;
    int col = t & 127, half = t >> 7;
    float s = 0.f;
    for (int r = half; r < 128; r += 2)
        s += partials[((size_t)g * 128 + r) * 128 + col];
    __shared__ float red[2][128];
    red[half][col] = s;
    __syncthreads();
    if (t < 128) partials2[(size_t)g * 128 + t] = red[0][t] + red[1][t];
}

// ---------------- K4b: final stats -> scale/shift per channel ----------------
__global__ __launch_bounds__(128) void k4b_stats(const float* __restrict__ partials2,
                                                 const float* __restrict__ gamma,
                                                 const float* __restrict__ beta,
                                                 float* __restrict__ ss) {
    int t = threadIdx.x;   // 0..127
    double s = 0.0;
    for (int i = 0; i < 64; ++i)
        s += (double)partials2[(size_t)i * 128 + t];
    __shared__ double red[128];
    red[t] = s;
    __syncthreads();
    if (t < 64) {
        double a = red[t], c = red[64 + t];
        double M = (double)B * NN * KNN;
        double mean = a / M;
        double var  = c / M - mean * mean;
        float sc = gamma[t] * rsqrtf((float)var + 1e-5f);
        float sh = beta[t] - (float)mean * sc;
        ss[t]      = sc;
        ss[64 + t] = sh;
    }
}

// ---------------- K5: normalize + leakyrelu + transpose to (B,O,N) ----------------
__global__ __launch_bounds__(256) void k5_out(const float* __restrict__ maxY,
                                              const float* __restrict__ minY,
                                              const float* __restrict__ ss,
                                              float* __restrict__ out) {
    __shared__ float tile[64][65];
    __shared__ float sc[64], sh[64];
    int t = threadIdx.x;
    if (t < 64) { sc[t] = ss[t]; sh[t] = ss[64 + t]; }
    int b  = blockIdx.x / (NN / 64);
    int n0 = (blockIdx.x % (NN / 64)) * 64;
    __syncthreads();
    #pragma unroll
    for (int it = 0; it < 16; ++it) {
        int i = it * 256 + t;
        int nl = i >> 6, o = i & 63;
        size_t off = ((size_t)(b * NN + n0 + nl)) * 64 + o;
        float s = sc[o];
        float v = (s >= 0.f) ? maxY[off] : minY[off];
        v = fmaf(v, s, sh[o]);
        v = (v >= 0.f) ? v : 0.2f * v;
        tile[nl][o] = v;
    }
    __syncthreads();
    #pragma unroll
    for (int it = 0; it < 16; ++it) {
        int i = it * 256 + t;
        int o = i >> 6, nl = i & 63;
        out[((size_t)(b * O + o)) * NN + n0 + nl] = tile[nl][o];
    }
}

extern "C" void kernel_launch(void* const* d_in, const int* in_sizes, int n_in,
                              void* d_out, int out_size, void* d_ws, size_t ws_size,
                              hipStream_t stream) {
    const float* x     = (const float*)d_in[0];
    const float* W     = (const float*)d_in[1];
    const float* gamma = (const float*)d_in[2];
    const float* beta  = (const float*)d_in[3];
    float* out = (float*)d_out;

    float* ws = (float*)d_ws;
    float* xt = ws;                                       // B*N*C
    float* xx = xt + (size_t)B * NN * C;                  // B*N
    int*   idx = (int*)(xx + (size_t)B * NN);             // B*N*KNN ints
    float* Z   = (float*)(idx + (size_t)B * NN * KNN);    // B*N*O
    float* Z2  = Z + (size_t)B * NN * O;                  // B*N*O
    float* maxY = Z2 + (size_t)B * NN * O;                // B*N*O
    float* minY = maxY + (size_t)B * NN * O;              // B*N*O
    float* partials  = minY + (size_t)B * NN * O;         // (B*N/4)*128
    float* partials2 = partials + (size_t)(B * NN / 4) * 128;  // 64*128
    float* ss = partials2 + 64 * 128;                     // 128

    k1_transpose<<<B * (NN / 64), 256, 0, stream>>>(x, xt, xx);
    k2_knn<<<B * (NN / NQ), 256, 0, stream>>>(xt, xx, idx);
    k3a_gemm<<<B * (NN / 16), 256, 0, stream>>>(xt, W, Z, Z2);
    k3b_gather<<<B * (NN / 4), 256, 0, stream>>>(Z, Z2, idx, maxY, minY, partials);
    k4a_reduce<<<64, 256, 0, stream>>>(partials, partials2);
    k4b_stats<<<1, 128, 0, stream>>>(partials2, gamma, beta, ss);
    k5_out<<<B * (NN / 64), 256, 0, stream>>>(maxY, minY, ss, out);
}

// Round 4
// 1288.885 us; speedup vs baseline: 2.3423x; 2.3423x over previous
//
#include <hip/hip_runtime.h>
#include <hip/hip_bf16.h>
#include <math.h>

#define B 8
#define C 64
#define NN 4096
#define O 64
#define KNN 20

typedef float f32x4 __attribute__((ext_vector_type(4)));
typedef short short8_t __attribute__((ext_vector_type(8)));

__device__ inline uint32_t fkey(float f) {
    uint32_t u = __float_as_uint(f);
    return u ^ (((uint32_t)((int32_t)u >> 31)) | 0x80000000u);
}

// ---------------- K1: x (B,C,N) -> xt f32 (B,N,C) + xh bf16 (B,N,C), xx = sum_c x^2 ----------------
__global__ __launch_bounds__(256) void k1_split(const float* __restrict__ x,
                                                float* __restrict__ xt,
                                                __hip_bfloat16* __restrict__ xh,
                                                float* __restrict__ xx) {
    __shared__ float tile[64][65];
    int b  = blockIdx.x / (NN / 64);
    int n0 = (blockIdx.x % (NN / 64)) * 64;
    int t = threadIdx.x;
    #pragma unroll
    for (int it = 0; it < 16; ++it) {
        int i = it * 256 + t;
        int c = i >> 6, n = i & 63;
        tile[c][n] = x[(size_t)b * C * NN + (size_t)c * NN + n0 + n];
    }
    __syncthreads();
    #pragma unroll
    for (int it = 0; it < 16; ++it) {
        int i = it * 256 + t;
        int n = i >> 6, c = i & 63;
        float v = tile[c][n];
        size_t off = ((size_t)(b * NN + n0 + n)) * C + c;
        xt[off] = v;
        xh[off] = __float2bfloat16(v);
    }
    if (t < 64) {
        float s = 0.f;
        #pragma unroll
        for (int c = 0; c < 64; ++c) { float v = tile[c][t]; s = fmaf(v, v, s); }
        xx[(size_t)b * NN + t + n0] = s;
    }
}

// ---------------- K2: bf16-MFMA approx filter -> top-32 -> exact f32 rerank -> top-20 ----------------
// block = 256 threads (4 waves), 16 queries/block. Wave w owns candidate strip
// [w*1024,(w+1)*1024) in 4 chunks of 256 (16 MFMA tiles of 16 cols).
// Approx keys are bf16-rank-noise (sigma~0.03) — used ONLY to pick 32 candidates;
// final ranking recomputes dist in f32 with Round-1's exact arithmetic.
__global__ __launch_bounds__(256) void k2_knn(const __hip_bfloat16* __restrict__ xh,
                                              const float* __restrict__ xt,
                                              const float* __restrict__ xx,
                                              int* __restrict__ idx) {
    int b  = blockIdx.x >> 8;
    int n0 = (blockIdx.x & 255) << 4;
    int t = threadIdx.x;
    int w = t >> 6, lane = t & 63;
    int laneid = lane & 15, grp = lane >> 4;

    const __hip_bfloat16* xhb = xh + (size_t)b * NN * 64;
    const float* xxb = xx + (size_t)b * NN;
    const float* xtb = xt + (size_t)b * NN * 64;

    // A fragments: row = query n0+laneid, k = grp*8 .. grp*8+7 (and +32)
    size_t qoff = (size_t)(n0 + laneid) * 64 + grp * 8;
    short8_t Ah0 = *(const short8_t*)(xhb + qoff);
    short8_t Ah1 = *(const short8_t*)(xhb + qoff + 32);

    // per-wave top-20 slots per j (query = grp*4+j): slot0 on 16 lanes, slot1 on lanes 0-3
    uint32_t sk0[4], sk1[4], sc0[4], sc1[4];
    uint32_t thr[4], thc[4];
    int mnl[4], mns[4];
    #pragma unroll
    for (int j = 0; j < 4; ++j) {
        sk0[j] = 0; sk1[j] = 0;
        sc0[j] = 0xFFFFFFFFu; sc1[j] = 0xFFFFFFFFu;
        thr[j] = 0; thc[j] = 0xFFFFFFFFu;
        mnl[j] = 0; mns[j] = 0;
    }

    uint32_t key[16][4];

    #pragma unroll 1
    for (int c = 0; c < 4; ++c) {
        int cbase = w * 1024 + c * 256;
        // ---- GEMM phase: 16 tiles of 16 candidates, bf16-only (2 MFMA/tile) ----
        #pragma unroll
        for (int tl = 0; tl < 16; ++tl) {
            int cand_i = cbase + tl * 16 + laneid;
            size_t coff = (size_t)cand_i * 64 + grp * 8;
            short8_t Bh0 = *(const short8_t*)(xhb + coff);
            short8_t Bh1 = *(const short8_t*)(xhb + coff + 32);
            f32x4 acc = {0.f, 0.f, 0.f, 0.f};
            acc = __builtin_amdgcn_mfma_f32_16x16x32_bf16(Ah0, Bh0, acc, 0, 0, 0);
            acc = __builtin_amdgcn_mfma_f32_16x16x32_bf16(Ah1, Bh1, acc, 0, 0, 0);
            float xxc = xxb[cand_i];
            #pragma unroll
            for (int j = 0; j < 4; ++j)
                key[tl][j] = fkey(fmaf(acc[j], 2.f, -xxc));   // approx rank key
        }
        // ---- selection phase: maintain per-wave top-20 ----
        #pragma unroll
        for (int j = 0; j < 4; ++j) {
            uint32_t thrv = thr[j], thcv = thc[j];
            int ml = mnl[j], ms = mns[j];
            #pragma unroll 1
            while (true) {
                uint32_t bk = 0; int bt = 0;
                #pragma unroll
                for (int tl = 0; tl < 16; ++tl)
                    if (key[tl][j] > bk) { bk = key[tl][j]; bt = tl; }
                uint32_t bc = (uint32_t)(cbase + (bt << 4) + laneid);
                #pragma unroll
                for (int off = 1; off <= 8; off <<= 1) {
                    uint32_t ok = __shfl_xor(bk, off);
                    uint32_t oc = __shfl_xor(bc, off);
                    if (ok > bk || (ok == bk && oc < bc)) { bk = ok; bc = oc; }
                }
                if (!(bk > thrv || (bk == thrv && bc < thcv))) break;
                if (laneid == ml) {
                    if (ms == 0) { sk0[j] = bk; sc0[j] = bc; }
                    else         { sk1[j] = bk; sc1[j] = bc; }
                }
                int wt = (int)(bc & 255u) >> 4;
                bool winlane = (laneid == (int)(bc & 15u));
                #pragma unroll
                for (int tl = 0; tl < 16; ++tl)
                    if (winlane && tl == wt) key[tl][j] = 0;
                // argmin over slots (tie-break TOTAL: key, then higher col, then lower lane)
                uint32_t mk = sk0[j], mc = sc0[j]; int s = 0;
                uint32_t k1v = (laneid < 4) ? sk1[j] : 0xFFFFFFFFu;
                if (k1v < mk || (k1v == mk && sc1[j] > mc)) { mk = k1v; mc = sc1[j]; s = 1; }
                int mlane = laneid;
                #pragma unroll
                for (int off = 1; off <= 8; off <<= 1) {
                    uint32_t omk = __shfl_xor(mk, off);
                    uint32_t omc = __shfl_xor(mc, off);
                    int ola = __shfl_xor(mlane, off);
                    int os  = __shfl_xor(s, off);
                    if (omk < mk ||
                        (omk == mk && (omc > mc || (omc == mc && ola < mlane)))) {
                        mk = omk; mc = omc; mlane = ola; s = os;
                    }
                }
                thrv = mk; thcv = mc; ml = mlane; ms = s;
            }
            thr[j] = thrv; thc[j] = thcv; mnl[j] = ml; mns[j] = ms;
        }
    }

    // ---- stage per-wave lists + query f32 rows ----
    __shared__ uint2 mbuf[16][4][20];   // [query][wave][slot]
    __shared__ uint32_t cand[16][32];   // approx top-32 cols per query
    __shared__ uint32_t rkk[16][32];    // exact f32 keys
    __shared__ float qrow[16][64];      // f32 query rows
    #pragma unroll
    for (int j = 0; j < 4; ++j) {
        int q = grp * 4 + j;
        mbuf[q][w][laneid] = make_uint2(sk0[j], sc0[j]);
        if (laneid < 4) mbuf[q][w][16 + laneid] = make_uint2(sk1[j], sc1[j]);
    }
    #pragma unroll
    for (int i = 0; i < 4; ++i) {
        int e = i * 256 + t;
        int r = e >> 6, cc = e & 63;
        qrow[r][cc] = xtb[(size_t)(n0 + r) * 64 + cc];
    }
    __syncthreads();

    // ---- merge 80 -> approx top-32 per query ----
    {
        int q = w * 4 + grp;
        const uint2* mb = &mbuf[q][0][0];
        uint2 e0 = mb[laneid], e1 = mb[16 + laneid], e2 = mb[32 + laneid],
              e3 = mb[48 + laneid], e4 = mb[64 + laneid];
        #pragma unroll 1
        for (int r = 0; r < 32; ++r) {
            uint32_t bk = 0, bc = 0xFFFFFFFFu;
            if (e0.x > bk || (e0.x == bk && e0.y < bc)) { bk = e0.x; bc = e0.y; }
            if (e1.x > bk || (e1.x == bk && e1.y < bc)) { bk = e1.x; bc = e1.y; }
            if (e2.x > bk || (e2.x == bk && e2.y < bc)) { bk = e2.x; bc = e2.y; }
            if (e3.x > bk || (e3.x == bk && e3.y < bc)) { bk = e3.x; bc = e3.y; }
            if (e4.x > bk || (e4.x == bk && e4.y < bc)) { bk = e4.x; bc = e4.y; }
            #pragma unroll
            for (int off = 1; off <= 8; off <<= 1) {
                uint32_t ok = __shfl_xor(bk, off);
                uint32_t oc = __shfl_xor(bc, off);
                if (ok > bk || (ok == bk && oc < bc)) { bk = ok; bc = oc; }
            }
            if (e0.y == bc) e0.x = 0;
            if (e1.y == bc) e1.x = 0;
            if (e2.y == bc) e2.x = 0;
            if (e3.y == bc) e3.x = 0;
            if (e4.y == bc) e4.x = 0;
            if (laneid == 0) cand[q][r] = bc;
        }
    }
    __syncthreads();

    // ---- exact f32 rerank of 32 candidates per query (Round-1 arithmetic) ----
    int rq = t >> 4, rs = t & 15;
    float qxx = xxb[n0 + rq];
    const float4* qr = (const float4*)qrow[rq];
    uint32_t mycol[2], mykey[2];
    #pragma unroll
    for (int e = 0; e < 2; ++e) {
        uint32_t col = cand[rq][rs + 16 * e];
        const float4* cr = (const float4*)(xtb + (size_t)col * 64);
        float a = 0.f;
        #pragma unroll
        for (int i = 0; i < 16; ++i) {
            float4 qv = qr[i], cv = cr[i];
            a = fmaf(qv.x, cv.x, a); a = fmaf(qv.y, cv.y, a);
            a = fmaf(qv.z, cv.z, a); a = fmaf(qv.w, cv.w, a);
        }
        float d = 2.f * a - qxx - xxb[col];
        mycol[e] = col;
        mykey[e] = fkey(d);
        rkk[rq][rs + 16 * e] = mykey[e];
    }
    __syncthreads();
    size_t ob = ((size_t)(b * NN) + n0 + rq) * KNN;
    #pragma unroll
    for (int e = 0; e < 2; ++e) {
        uint32_t ke = mykey[e], ce = mycol[e];
        int rank = 0;
        #pragma unroll
        for (int jj = 0; jj < 32; ++jj) {
            uint32_t kj = rkk[rq][jj], cj = cand[rq][jj];
            rank += (kj > ke || (kj == ke && cj < ce)) ? 1 : 0;
        }
        if (rank < KNN) idx[ob + rank] = (int)ce;
    }
}

// ---------------- K3a: Z = xt @ W0^T, Z2 = xt @ (W1-W0)^T ----------------
__global__ __launch_bounds__(256) void k3a_gemm(const float* __restrict__ xt,
                                                const float* __restrict__ W,
                                                float* __restrict__ Z,
                                                float* __restrict__ Z2) {
    __shared__ float W0t[64][65];
    __shared__ float W21t[64][65];
    __shared__ float xs[16][64];
    int t = threadIdx.x;
    #pragma unroll
    for (int it = 0; it < 16; ++it) {
        int i = it * 256 + t;
        int o = i >> 6, c = i & 63;
        float w0 = W[o * 128 + c];
        float w1 = W[o * 128 + 64 + c];
        W0t[c][o]  = w0;
        W21t[c][o] = w1 - w0;
    }
    int b  = blockIdx.x / (NN / 16);
    int nb = (blockIdx.x % (NN / 16)) * 16;
    #pragma unroll
    for (int it = 0; it < 4; ++it) {
        int i = it * 256 + t;
        int r = i >> 6, c = i & 63;
        xs[r][c] = xt[((size_t)(b * NN + nb + r)) * C + c];
    }
    __syncthreads();
    int o = t & 63, rg = t >> 6;
    #pragma unroll
    for (int rr = 0; rr < 4; ++rr) {
        int r = rg * 4 + rr;
        float z = 0.f, z2 = 0.f;
        #pragma unroll
        for (int c = 0; c < 64; ++c) {
            float xv = xs[r][c];
            z  = fmaf(xv, W0t[c][o],  z);
            z2 = fmaf(xv, W21t[c][o], z2);
        }
        size_t off = ((size_t)(b * NN + nb + r)) * 64 + o;
        Z[off]  = z;
        Z2[off] = z2;
    }
}

// ---------------- K3b: gather neighbors, per-(b,n,o) max/min over k, block-partial sums ----------------
__global__ __launch_bounds__(256) void k3b_gather(const float* __restrict__ Z,
                                                  const float* __restrict__ Z2,
                                                  const int* __restrict__ idx,
                                                  float* __restrict__ maxY,
                                                  float* __restrict__ minY,
                                                  float* __restrict__ partials) {
    int t = threadIdx.x;
    int p = t >> 6, o = t & 63;
    int b = blockIdx.x / (NN / 4);
    int n = (blockIdx.x % (NN / 4)) * 4 + p;
    size_t base = (size_t)(b * NN + n);
    float z2 = Z2[base * 64 + o];
    __shared__ int sidx[4][KNN];
    if (o < KNN) sidx[p][o] = idx[base * KNN + o];
    __syncthreads();
    const float* Zb = Z + (size_t)b * NN * 64;
    float s1 = 0.f, s2 = 0.f, mx = -INFINITY, mn = INFINITY;
    #pragma unroll
    for (int k = 0; k < KNN; ++k) {
        float y = Zb[(size_t)sidx[p][k] * 64 + o] + z2;
        s1 += y;
        s2 = fmaf(y, y, s2);
        mx = fmaxf(mx, y);
        mn = fminf(mn, y);
    }
    maxY[base * 64 + o] = mx;
    minY[base * 64 + o] = mn;
    __shared__ float red[2][4][64];
    red[0][p][o] = s1;
    red[1][p][o] = s2;
    __syncthreads();
    if (t < 64) {
        float a = red[0][0][t] + red[0][1][t] + red[0][2][t] + red[0][3][t];
        float c = red[1][0][t] + red[1][1][t] + red[1][2][t] + red[1][3][t];
        partials[(size_t)blockIdx.x * 128 + t]      = a;
        partials[(size_t)blockIdx.x * 128 + 64 + t] = c;
    }
}

// ---------------- K4a: reduce 8192 partial rows -> 64 rows ----------------
__global__ __launch_bounds__(256) void k4a_reduce(const float* __restrict__ partials,
                                                  float* __restrict__ partials2) {
    int g = blockIdx.x;          // 0..63
    int t = threadIdx.x;
    int col = t & 127, half = t >> 7;
    float s = 0.f;
    for (int r = half; r < 128; r += 2)
        s += partials[((size_t)g * 128 + r) * 128 + col];
    __shared__ float red[2][128];
    red[half][col] = s;
    __syncthreads();
    if (t < 128) partials2[(size_t)g * 128 + t] = red[0][t] + red[1][t];
}

// ---------------- K4b: final stats -> scale/shift per channel ----------------
__global__ __launch_bounds__(128) void k4b_stats(const float* __restrict__ partials2,
                                                 const float* __restrict__ gamma,
                                                 const float* __restrict__ beta,
                                                 float* __restrict__ ss) {
    int t = threadIdx.x;   // 0..127
    double s = 0.0;
    for (int i = 0; i < 64; ++i)
        s += (double)partials2[(size_t)i * 128 + t];
    __shared__ double red[128];
    red[t] = s;
    __syncthreads();
    if (t < 64) {
        double a = red[t], c = red[64 + t];
        double M = (double)B * NN * KNN;
        double mean = a / M;
        double var  = c / M - mean * mean;
        float sc = gamma[t] * rsqrtf((float)var + 1e-5f);
        float sh = beta[t] - (float)mean * sc;
        ss[t]      = sc;
        ss[64 + t] = sh;
    }
}

// ---------------- K5: normalize + leakyrelu + transpose to (B,O,N) ----------------
__global__ __launch_bounds__(256) void k5_out(const float* __restrict__ maxY,
                                              const float* __restrict__ minY,
                                              const float* __restrict__ ss,
                                              float* __restrict__ out) {
    __shared__ float tile[64][65];
    __shared__ float sc[64], sh[64];
    int t = threadIdx.x;
    if (t < 64) { sc[t] = ss[t]; sh[t] = ss[64 + t]; }
    int b  = blockIdx.x / (NN / 64);
    int n0 = (blockIdx.x % (NN / 64)) * 64;
    __syncthreads();
    #pragma unroll
    for (int it = 0; it < 16; ++it) {
        int i = it * 256 + t;
        int nl = i >> 6, o = i & 63;
        size_t off = ((size_t)(b * NN + n0 + nl)) * 64 + o;
        float s = sc[o];
        float v = (s >= 0.f) ? maxY[off] : minY[off];
        v = fmaf(v, s, sh[o]);
        v = (v >= 0.f) ? v : 0.2f * v;
        tile[nl][o] = v;
    }
    __syncthreads();
    #pragma unroll
    for (int it = 0; it < 16; ++it) {
        int i = it * 256 + t;
        int o = i >> 6, nl = i & 63;
        out[((size_t)(b * O + o)) * NN + n0 + nl] = tile[nl][o];
    }
}

extern "C" void kernel_launch(void* const* d_in, const int* in_sizes, int n_in,
                              void* d_out, int out_size, void* d_ws, size_t ws_size,
                              hipStream_t stream) {
    const float* x     = (const float*)d_in[0];
    const float* W     = (const float*)d_in[1];
    const float* gamma = (const float*)d_in[2];
    const float* beta  = (const float*)d_in[3];
    float* out = (float*)d_out;

    float* ws = (float*)d_ws;
    float* xx = ws;                                                // B*N
    float* xt = xx + (size_t)B * NN;                               // B*N*C f32
    __hip_bfloat16* xh = (__hip_bfloat16*)(xt + (size_t)B * NN * C); // B*N*C bf16
    int*   idx = (int*)(xh + (size_t)B * NN * C);                  // B*N*KNN ints
    float* Z   = (float*)(idx + (size_t)B * NN * KNN);             // B*N*O
    float* Z2  = Z + (size_t)B * NN * O;
    float* maxY = Z2 + (size_t)B * NN * O;
    float* minY = maxY + (size_t)B * NN * O;
    float* partials  = minY + (size_t)B * NN * O;                  // (B*N/4)*128
    float* partials2 = partials + (size_t)(B * NN / 4) * 128;      // 64*128
    float* ss = partials2 + 64 * 128;                              // 128

    k1_split<<<B * (NN / 64), 256, 0, stream>>>(x, xt, xh, xx);
    k2_knn<<<B * (NN / 16), 256, 0, stream>>>(xh, xt, xx, idx);
    k3a_gemm<<<B * (NN / 16), 256, 0, stream>>>(xt, W, Z, Z2);
    k3b_gather<<<B * (NN / 4), 256, 0, stream>>>(Z, Z2, idx, maxY, minY, partials);
    k4a_reduce<<<64, 256, 0, stream>>>(partials, partials2);
    k4b_stats<<<1, 128, 0, stream>>>(partials2, gamma, beta, ss);
    k5_out<<<B * (NN / 64), 256, 0, stream>>>(maxY, minY, ss, out);
}

// Round 5
// 515.733 us; speedup vs baseline: 5.8538x; 2.4991x over previous
//
#include <hip/hip_runtime.h>
#include <hip/hip_bf16.h>
#include <math.h>

#define B 8
#define C 64
#define NN 4096
#define O 64
#define KNN 20

typedef float f32x4 __attribute__((ext_vector_type(4)));
typedef short short8_t __attribute__((ext_vector_type(8)));

__device__ inline uint32_t fkey(float f) {
    uint32_t u = __float_as_uint(f);
    return u ^ (((uint32_t)((int32_t)u >> 31)) | 0x80000000u);
}

// ---------------- K1: x (B,C,N) -> xt f32 (B,N,C) + xh bf16 (B,N,C), xx = sum_c x^2 ----------------
__global__ __launch_bounds__(256) void k1_split(const float* __restrict__ x,
                                                float* __restrict__ xt,
                                                __hip_bfloat16* __restrict__ xh,
                                                float* __restrict__ xx) {
    __shared__ float tile[64][65];
    int b  = blockIdx.x / (NN / 64);
    int n0 = (blockIdx.x % (NN / 64)) * 64;
    int t = threadIdx.x;
    #pragma unroll
    for (int it = 0; it < 16; ++it) {
        int i = it * 256 + t;
        int c = i >> 6, n = i & 63;
        tile[c][n] = x[(size_t)b * C * NN + (size_t)c * NN + n0 + n];
    }
    __syncthreads();
    #pragma unroll
    for (int it = 0; it < 16; ++it) {
        int i = it * 256 + t;
        int n = i >> 6, c = i & 63;
        float v = tile[c][n];
        size_t off = ((size_t)(b * NN + n0 + n)) * C + c;
        xt[off] = v;
        xh[off] = __float2bfloat16(v);
    }
    if (t < 64) {
        float s = 0.f;
        #pragma unroll
        for (int c = 0; c < 64; ++c) { float v = tile[c][t]; s = fmaf(v, v, s); }
        xx[(size_t)b * NN + t + n0] = s;
    }
}

// ---------------- K2: bf16-MFMA approx filter (per-lane queues) -> top-32 -> exact f32 rerank ----------------
// block = 256 threads (4 waves), 16 queries/block. Wave w owns candidate strip
// [w*1024,(w+1)*1024) in 4 chunks of 256 (16 MFMA tiles of 16 cols).
// Each lane keeps a sorted top-12 queue per query (its 64 candidates); wave top-24
// extracted by tournament over queue heads; block merge 96->32; exact f32 rerank.
__global__ __launch_bounds__(256) void k2_knn(const __hip_bfloat16* __restrict__ xh,
                                              const float* __restrict__ xt,
                                              const float* __restrict__ xx,
                                              int* __restrict__ idx) {
    int b  = blockIdx.x >> 8;
    int n0 = (blockIdx.x & 255) << 4;
    int t = threadIdx.x;
    int w = t >> 6, lane = t & 63;
    int laneid = lane & 15, grp = lane >> 4;

    const __hip_bfloat16* xhb = xh + (size_t)b * NN * 64;
    const float* xxb = xx + (size_t)b * NN;
    const float* xtb = xt + (size_t)b * NN * 64;

    // A fragments: row = query n0+laneid, k = grp*8 .. grp*8+7 (and +32)
    size_t qoff = (size_t)(n0 + laneid) * 64 + grp * 8;
    short8_t Ah0 = *(const short8_t*)(xhb + qoff);
    short8_t Ah1 = *(const short8_t*)(xhb + qoff + 32);

    // per-lane sorted queues, descending: qq[j][0] >= ... >= qq[j][11].
    // entry = (approx_key & ~63) | (chunk*16 + tile)  — col reconstructable.
    uint32_t qq[4][12];
    #pragma unroll
    for (int j = 0; j < 4; ++j)
        #pragma unroll
        for (int i = 0; i < 12; ++i) qq[j][i] = 0;

    #pragma unroll 1
    for (int c = 0; c < 4; ++c) {
        int cbase = w * 1024 + c * 256;
        #pragma unroll
        for (int tl = 0; tl < 16; ++tl) {
            int cand_i = cbase + tl * 16 + laneid;
            size_t coff = (size_t)cand_i * 64 + grp * 8;
            short8_t Bh0 = *(const short8_t*)(xhb + coff);
            short8_t Bh1 = *(const short8_t*)(xhb + coff + 32);
            f32x4 acc = {0.f, 0.f, 0.f, 0.f};
            acc = __builtin_amdgcn_mfma_f32_16x16x32_bf16(Ah0, Bh0, acc, 0, 0, 0);
            acc = __builtin_amdgcn_mfma_f32_16x16x32_bf16(Ah1, Bh1, acc, 0, 0, 0);
            float xxc = xxb[cand_i];
            #pragma unroll
            for (int j = 0; j < 4; ++j) {
                uint32_t nv = (fkey(fmaf(acc[j], 2.f, -xxc)) & 0xFFFFFFC0u)
                            | (uint32_t)(c * 16 + tl);
                // branchless sorted insert (keeps top-12)
                #pragma unroll
                for (int i = 0; i < 12; ++i) {
                    uint32_t cur = qq[j][i];
                    uint32_t hi = cur > nv ? cur : nv;
                    uint32_t lo = cur > nv ? nv : cur;
                    qq[j][i] = hi;
                    nv = lo;
                }
            }
        }
    }

    __shared__ uint2 mbuf[16][4][24];   // [query][wave][slot] = (packed key, col)
    __shared__ uint32_t cand[16][32];   // approx top-32 cols per query
    __shared__ uint32_t rkk[16][32];    // exact f32 keys
    __shared__ float qrow[16][64];      // f32 query rows

    // stage f32 query rows while queues are extracted
    #pragma unroll
    for (int i = 0; i < 4; ++i) {
        int e = i * 256 + t;
        int r = e >> 6, cc = e & 63;
        qrow[r][cc] = xtb[(size_t)(n0 + r) * 64 + cc];
    }

    // ---- wave top-24 extraction: tournament over 16 queue heads ----
    #pragma unroll 1
    for (int r = 0; r < 24; ++r) {
        #pragma unroll
        for (int j = 0; j < 4; ++j) {
            uint32_t bk = qq[j][0];
            uint32_t bl = (uint32_t)laneid;
            #pragma unroll
            for (int off = 1; off <= 8; off <<= 1) {
                uint32_t ok = __shfl_xor(bk, off);
                uint32_t ol = __shfl_xor(bl, off);
                if (ok > bk || (ok == bk && ol < bl)) { bk = ok; bl = ol; }
            }
            if ((uint32_t)laneid == bl) {   // winner pops its queue
                #pragma unroll
                for (int i = 0; i < 11; ++i) qq[j][i] = qq[j][i + 1];
                qq[j][11] = 0;
            }
            if (laneid == 0) {
                uint32_t id = bk & 63u;
                uint32_t col = (uint32_t)(w * 1024)
                             + ((id >> 4) << 8) + ((id & 15u) << 4) + bl;
                mbuf[grp * 4 + j][w][r] = make_uint2(bk, col);
            }
        }
    }
    __syncthreads();

    // ---- merge 96 -> approx top-32 per query ----
    {
        int q = w * 4 + grp;
        const uint2* mb = &mbuf[q][0][0];
        uint2 e0 = mb[laneid],      e1 = mb[16 + laneid], e2 = mb[32 + laneid],
              e3 = mb[48 + laneid], e4 = mb[64 + laneid], e5 = mb[80 + laneid];
        #pragma unroll 1
        for (int r = 0; r < 32; ++r) {
            uint32_t bk = 0, bc = 0xFFFFFFFFu;
            if (e0.x > bk || (e0.x == bk && e0.y < bc)) { bk = e0.x; bc = e0.y; }
            if (e1.x > bk || (e1.x == bk && e1.y < bc)) { bk = e1.x; bc = e1.y; }
            if (e2.x > bk || (e2.x == bk && e2.y < bc)) { bk = e2.x; bc = e2.y; }
            if (e3.x > bk || (e3.x == bk && e3.y < bc)) { bk = e3.x; bc = e3.y; }
            if (e4.x > bk || (e4.x == bk && e4.y < bc)) { bk = e4.x; bc = e4.y; }
            if (e5.x > bk || (e5.x == bk && e5.y < bc)) { bk = e5.x; bc = e5.y; }
            #pragma unroll
            for (int off = 1; off <= 8; off <<= 1) {
                uint32_t ok = __shfl_xor(bk, off);
                uint32_t oc = __shfl_xor(bc, off);
                if (ok > bk || (ok == bk && oc < bc)) { bk = ok; bc = oc; }
            }
            if (e0.y == bc) e0.x = 0;
            if (e1.y == bc) e1.x = 0;
            if (e2.y == bc) e2.x = 0;
            if (e3.y == bc) e3.x = 0;
            if (e4.y == bc) e4.x = 0;
            if (e5.y == bc) e5.x = 0;
            if (laneid == 0) cand[q][r] = bc;
        }
    }
    __syncthreads();

    // ---- exact f32 rerank of 32 candidates per query (Round-1 arithmetic) ----
    int rq = t >> 4, rs = t & 15;
    float qxx = xxb[n0 + rq];
    const float4* qr = (const float4*)qrow[rq];
    uint32_t mycol[2], mykey[2];
    #pragma unroll
    for (int e = 0; e < 2; ++e) {
        uint32_t col = cand[rq][rs + 16 * e];
        const float4* cr = (const float4*)(xtb + (size_t)col * 64);
        float a = 0.f;
        #pragma unroll
        for (int i = 0; i < 16; ++i) {
            float4 qv = qr[i], cv = cr[i];
            a = fmaf(qv.x, cv.x, a); a = fmaf(qv.y, cv.y, a);
            a = fmaf(qv.z, cv.z, a); a = fmaf(qv.w, cv.w, a);
        }
        float d = 2.f * a - qxx - xxb[col];
        mycol[e] = col;
        mykey[e] = fkey(d);
        rkk[rq][rs + 16 * e] = mykey[e];
    }
    __syncthreads();
    size_t ob = ((size_t)(b * NN) + n0 + rq) * KNN;
    #pragma unroll
    for (int e = 0; e < 2; ++e) {
        uint32_t ke = mykey[e], ce = mycol[e];
        int rank = 0;
        #pragma unroll
        for (int jj = 0; jj < 32; ++jj) {
            uint32_t kj = rkk[rq][jj], cj = cand[rq][jj];
            rank += (kj > ke || (kj == ke && cj < ce)) ? 1 : 0;
        }
        if (rank < KNN) idx[ob + rank] = (int)ce;
    }
}

// ---------------- K3a: Z = xt @ W0^T, Z2 = xt @ (W1-W0)^T ----------------
__global__ __launch_bounds__(256) void k3a_gemm(const float* __restrict__ xt,
                                                const float* __restrict__ W,
                                                float* __restrict__ Z,
                                                float* __restrict__ Z2) {
    __shared__ float W0t[64][65];
    __shared__ float W21t[64][65];
    __shared__ float xs[16][64];
    int t = threadIdx.x;
    #pragma unroll
    for (int it = 0; it < 16; ++it) {
        int i = it * 256 + t;
        int o = i >> 6, c = i & 63;
        float w0 = W[o * 128 + c];
        float w1 = W[o * 128 + 64 + c];
        W0t[c][o]  = w0;
        W21t[c][o] = w1 - w0;
    }
    int b  = blockIdx.x / (NN / 16);
    int nb = (blockIdx.x % (NN / 16)) * 16;
    #pragma unroll
    for (int it = 0; it < 4; ++it) {
        int i = it * 256 + t;
        int r = i >> 6, c = i & 63;
        xs[r][c] = xt[((size_t)(b * NN + nb + r)) * C + c];
    }
    __syncthreads();
    int o = t & 63, rg = t >> 6;
    #pragma unroll
    for (int rr = 0; rr < 4; ++rr) {
        int r = rg * 4 + rr;
        float z = 0.f, z2 = 0.f;
        #pragma unroll
        for (int c = 0; c < 64; ++c) {
            float xv = xs[r][c];
            z  = fmaf(xv, W0t[c][o],  z);
            z2 = fmaf(xv, W21t[c][o], z2);
        }
        size_t off = ((size_t)(b * NN + nb + r)) * 64 + o;
        Z[off]  = z;
        Z2[off] = z2;
    }
}

// ---------------- K3b: gather neighbors, per-(b,n,o) max/min over k, block-partial sums ----------------
__global__ __launch_bounds__(256) void k3b_gather(const float* __restrict__ Z,
                                                  const float* __restrict__ Z2,
                                                  const int* __restrict__ idx,
                                                  float* __restrict__ maxY,
                                                  float* __restrict__ minY,
                                                  float* __restrict__ partials) {
    int t = threadIdx.x;
    int p = t >> 6, o = t & 63;
    int b = blockIdx.x / (NN / 4);
    int n = (blockIdx.x % (NN / 4)) * 4 + p;
    size_t base = (size_t)(b * NN + n);
    float z2 = Z2[base * 64 + o];
    __shared__ int sidx[4][KNN];
    if (o < KNN) sidx[p][o] = idx[base * KNN + o];
    __syncthreads();
    const float* Zb = Z + (size_t)b * NN * 64;
    float s1 = 0.f, s2 = 0.f, mx = -INFINITY, mn = INFINITY;
    #pragma unroll
    for (int k = 0; k < KNN; ++k) {
        float y = Zb[(size_t)sidx[p][k] * 64 + o] + z2;
        s1 += y;
        s2 = fmaf(y, y, s2);
        mx = fmaxf(mx, y);
        mn = fminf(mn, y);
    }
    maxY[base * 64 + o] = mx;
    minY[base * 64 + o] = mn;
    __shared__ float red[2][4][64];
    red[0][p][o] = s1;
    red[1][p][o] = s2;
    __syncthreads();
    if (t < 64) {
        float a = red[0][0][t] + red[0][1][t] + red[0][2][t] + red[0][3][t];
        float c = red[1][0][t] + red[1][1][t] + red[1][2][t] + red[1][3][t];
        partials[(size_t)blockIdx.x * 128 + t]      = a;
        partials[(size_t)blockIdx.x * 128 + 64 + t] = c;
    }
}

// ---------------- K4a: reduce 8192 partial rows -> 64 rows ----------------
__global__ __launch_bounds__(256) void k4a_reduce(const float* __restrict__ partials,
                                                  float* __restrict__ partials2) {
    int g = blockIdx.x;          // 0..63
    int t = threadIdx.x;
    int col = t & 127, half = t >> 7;
    float s = 0.f;
    for (int r = half; r < 128; r += 2)
        s += partials[((size_t)g * 128 + r) * 128 + col];
    __shared__ float red[2][128];
    red[half][col] = s;
    __syncthreads();
    if (t < 128) partials2[(size_t)g * 128 + t] = red[0][t] + red[1][t];
}

// ---------------- K4b: final stats -> scale/shift per channel ----------------
__global__ __launch_bounds__(128) void k4b_stats(const float* __restrict__ partials2,
                                                 const float* __restrict__ gamma,
                                                 const float* __restrict__ beta,
                                                 float* __restrict__ ss) {
    int t = threadIdx.x;   // 0..127
    double s = 0.0;
    for (int i = 0; i < 64; ++i)
        s += (double)partials2[(size_t)i * 128 + t];
    __shared__ double red[128];
    red[t] = s;
    __syncthreads();
    if (t < 64) {
        double a = red[t], c = red[64 + t];
        double M = (double)B * NN * KNN;
        double mean = a / M;
        double var  = c / M - mean * mean;
        float sc = gamma[t] * rsqrtf((float)var + 1e-5f);
        float sh = beta[t] - (float)mean * sc;
        ss[t]      = sc;
        ss[64 + t] = sh;
    }
}

// ---------------- K5: normalize + leakyrelu + transpose to (B,O,N) ----------------
__global__ __launch_bounds__(256) void k5_out(const float* __restrict__ maxY,
                                              const float* __restrict__ minY,
                                              const float* __restrict__ ss,
                                              float* __restrict__ out) {
    __shared__ float tile[64][65];
    __shared__ float sc[64], sh[64];
    int t = threadIdx.x;
    if (t < 64) { sc[t] = ss[t]; sh[t] = ss[64 + t]; }
    int b  = blockIdx.x / (NN / 64);
    int n0 = (blockIdx.x % (NN / 64)) * 64;
    __syncthreads();
    #pragma unroll
    for (int it = 0; it < 16; ++it) {
        int i = it * 256 + t;
        int nl = i >> 6, o = i & 63;
        size_t off = ((size_t)(b * NN + n0 + nl)) * 64 + o;
        float s = sc[o];
        float v = (s >= 0.f) ? maxY[off] : minY[off];
        v = fmaf(v, s, sh[o]);
        v = (v >= 0.f) ? v : 0.2f * v;
        tile[nl][o] = v;
    }
    __syncthreads();
    #pragma unroll
    for (int it = 0; it < 16; ++it) {
        int i = it * 256 + t;
        int o = i >> 6, nl = i & 63;
        out[((size_t)(b * O + o)) * NN + n0 + nl] = tile[nl][o];
    }
}

extern "C" void kernel_launch(void* const* d_in, const int* in_sizes, int n_in,
                              void* d_out, int out_size, void* d_ws, size_t ws_size,
                              hipStream_t stream) {
    const float* x     = (const float*)d_in[0];
    const float* W     = (const float*)d_in[1];
    const float* gamma = (const float*)d_in[2];
    const float* beta  = (const float*)d_in[3];
    float* out = (float*)d_out;

    float* ws = (float*)d_ws;
    float* xx = ws;                                                // B*N
    float* xt = xx + (size_t)B * NN;                               // B*N*C f32
    __hip_bfloat16* xh = (__hip_bfloat16*)(xt + (size_t)B * NN * C); // B*N*C bf16
    int*   idx = (int*)(xh + (size_t)B * NN * C);                  // B*N*KNN ints
    float* Z   = (float*)(idx + (size_t)B * NN * KNN);             // B*N*O
    float* Z2  = Z + (size_t)B * NN * O;
    float* maxY = Z2 + (size_t)B * NN * O;
    float* minY = maxY + (size_t)B * NN * O;
    float* partials  = minY + (size_t)B * NN * O;                  // (B*N/4)*128
    float* partials2 = partials + (size_t)(B * NN / 4) * 128;      // 64*128
    float* ss = partials2 + 64 * 128;                              // 128

    k1_split<<<B * (NN / 64), 256, 0, stream>>>(x, xt, xh, xx);
    k2_knn<<<B * (NN / 16), 256, 0, stream>>>(xh, xt, xx, idx);
    k3a_gemm<<<B * (NN / 16), 256, 0, stream>>>(xt, W, Z, Z2);
    k3b_gather<<<B * (NN / 4), 256, 0, stream>>>(Z, Z2, idx, maxY, minY, partials);
    k4a_reduce<<<64, 256, 0, stream>>>(partials, partials2);
    k4b_stats<<<1, 128, 0, stream>>>(partials2, gamma, beta, ss);
    k5_out<<<B * (NN / 64), 256, 0, stream>>>(maxY, minY, ss, out);
}

// Round 6
// 307.553 us; speedup vs baseline: 9.8162x; 1.6769x over previous
//
#include <hip/hip_runtime.h>
#include <hip/hip_bf16.h>
#include <math.h>

#define B 8
#define C 64
#define NN 4096
#define O 64
#define KNN 20

typedef float f32x4 __attribute__((ext_vector_type(4)));
typedef short short8_t __attribute__((ext_vector_type(8)));

__device__ inline uint32_t fkey(float f) {
    uint32_t u = __float_as_uint(f);
    return u ^ (((uint32_t)((int32_t)u >> 31)) | 0x80000000u);
}

__device__ inline uint32_t med3u(uint32_t a, uint32_t b, uint32_t c) {
    uint32_t r;
    asm("v_med3_u32 %0, %1, %2, %3" : "=v"(r) : "v"(a), "v"(b), "v"(c));
    return r;
}
__device__ inline uint32_t umax(uint32_t a, uint32_t b) { return a > b ? a : b; }

// ---------------- K1: x (B,C,N) -> xt f32 (B,N,C) + xh bf16 (B,N,C), xx = sum_c x^2 ----------------
__global__ __launch_bounds__(256) void k1_split(const float* __restrict__ x,
                                                float* __restrict__ xt,
                                                __hip_bfloat16* __restrict__ xh,
                                                float* __restrict__ xx) {
    __shared__ float tile[64][65];
    int b  = blockIdx.x / (NN / 64);
    int n0 = (blockIdx.x % (NN / 64)) * 64;
    int t = threadIdx.x;
    #pragma unroll
    for (int it = 0; it < 16; ++it) {
        int i = it * 256 + t;
        int c = i >> 6, n = i & 63;
        tile[c][n] = x[(size_t)b * C * NN + (size_t)c * NN + n0 + n];
    }
    __syncthreads();
    #pragma unroll
    for (int it = 0; it < 16; ++it) {
        int i = it * 256 + t;
        int n = i >> 6, c = i & 63;
        float v = tile[c][n];
        size_t off = ((size_t)(b * NN + n0 + n)) * C + c;
        xt[off] = v;
        xh[off] = __float2bfloat16(v);
    }
    if (t < 64) {
        float s = 0.f;
        #pragma unroll
        for (int c = 0; c < 64; ++c) { float v = tile[c][t]; s = fmaf(v, v, s); }
        xx[(size_t)b * NN + t + n0] = s;
    }
}

// ---------------- K2: bf16-MFMA approx filter (packed keys, med3 queues) -> top-32 -> exact f32 rerank ----------------
// block = 256 threads (4 waves), 16 queries/block. Wave w owns candidate strip
// [w*1024,(w+1)*1024) in 64 MFMA tiles of 16 cols. Each lane keeps a sorted
// top-12 queue per query; packed entry = (approx_key & 0xFFFFF000) | (4095-col)
// so ONE u32 max does compare + lower-col tie-break. Wave top-24 by tournament;
// block merge 96->32; exact f32 rerank (Round-1 arithmetic).
__global__ __launch_bounds__(256) void k2_knn(const __hip_bfloat16* __restrict__ xh,
                                              const float* __restrict__ xt,
                                              const float* __restrict__ xx,
                                              int* __restrict__ idx) {
    int b  = blockIdx.x >> 8;
    int n0 = (blockIdx.x & 255) << 4;
    int t = threadIdx.x;
    int w = t >> 6, lane = t & 63;
    int laneid = lane & 15, grp = lane >> 4;

    const __hip_bfloat16* xhb = xh + (size_t)b * NN * 64;
    const float* xxb = xx + (size_t)b * NN;
    const float* xtb = xt + (size_t)b * NN * 64;

    // A fragments: row = query n0+laneid, k = grp*8 .. grp*8+7 (and +32)
    size_t qoff = (size_t)(n0 + laneid) * 64 + grp * 8;
    short8_t Ah0 = *(const short8_t*)(xhb + qoff);
    short8_t Ah1 = *(const short8_t*)(xhb + qoff + 32);

    // per-lane sorted queues (desc), packed u32 entries
    uint32_t qq[4][12];
    #pragma unroll
    for (int j = 0; j < 4; ++j)
        #pragma unroll
        for (int i = 0; i < 12; ++i) qq[j][i] = 0;

    #pragma unroll 1
    for (int c = 0; c < 4; ++c) {
        int cbase = w * 1024 + c * 256;
        #pragma unroll
        for (int tl = 0; tl < 16; ++tl) {
            int cand_i = cbase + tl * 16 + laneid;
            size_t coff = (size_t)cand_i * 64 + grp * 8;
            short8_t Bh0 = *(const short8_t*)(xhb + coff);
            short8_t Bh1 = *(const short8_t*)(xhb + coff + 32);
            f32x4 acc = {0.f, 0.f, 0.f, 0.f};
            acc = __builtin_amdgcn_mfma_f32_16x16x32_bf16(Ah0, Bh0, acc, 0, 0, 0);
            acc = __builtin_amdgcn_mfma_f32_16x16x32_bf16(Ah1, Bh1, acc, 0, 0, 0);
            float xxc = xxb[cand_i];
            uint32_t invcol = 4095u - (uint32_t)cand_i;
            #pragma unroll
            for (int j = 0; j < 4; ++j) {
                uint32_t nv = (fkey(fmaf(acc[j], 2.f, -xxc)) & 0xFFFFF000u) | invcol;
                // sorted insert: all slots read OLD values -> independent med3 ops
                #pragma unroll
                for (int i = 11; i >= 1; --i)
                    qq[j][i] = med3u(qq[j][i - 1], qq[j][i], nv);
                qq[j][0] = umax(qq[j][0], nv);
            }
        }
    }

    __shared__ uint32_t mbuf[16][4][24];   // [query][wave][slot] = packed
    __shared__ uint32_t cand[16][32];      // approx top-32 cols per query
    __shared__ uint32_t rkk[16][32];       // exact f32 keys
    __shared__ float qrow[16][64];         // f32 query rows

    // stage f32 query rows
    #pragma unroll
    for (int i = 0; i < 4; ++i) {
        int e = i * 256 + t;
        int r = e >> 6, cc = e & 63;
        qrow[r][cc] = xtb[(size_t)(n0 + r) * 64 + cc];
    }

    // ---- wave top-24 extraction: tournament over 16 queue heads ----
    #pragma unroll 1
    for (int r = 0; r < 24; ++r) {
        #pragma unroll
        for (int j = 0; j < 4; ++j) {
            uint32_t bk = qq[j][0];
            #pragma unroll
            for (int off = 1; off <= 8; off <<= 1)
                bk = umax(bk, __shfl_xor(bk, off));
            bool win = (qq[j][0] == bk);   // packed values unique -> single winner
            #pragma unroll
            for (int i = 0; i < 11; ++i) qq[j][i] = win ? qq[j][i + 1] : qq[j][i];
            qq[j][11] = win ? 0u : qq[j][11];
            if (laneid == 0) mbuf[grp * 4 + j][w][r] = bk;
        }
    }
    __syncthreads();

    // ---- merge 96 -> approx top-32 per query ----
    {
        int q = w * 4 + grp;
        const uint32_t* mb = &mbuf[q][0][0];
        uint32_t e0 = mb[laneid],      e1 = mb[16 + laneid], e2 = mb[32 + laneid],
                 e3 = mb[48 + laneid], e4 = mb[64 + laneid], e5 = mb[80 + laneid];
        #pragma unroll 1
        for (int r = 0; r < 32; ++r) {
            uint32_t bk = umax(umax(umax(e0, e1), umax(e2, e3)), umax(e4, e5));
            #pragma unroll
            for (int off = 1; off <= 8; off <<= 1)
                bk = umax(bk, __shfl_xor(bk, off));
            e0 = (e0 == bk) ? 0u : e0;
            e1 = (e1 == bk) ? 0u : e1;
            e2 = (e2 == bk) ? 0u : e2;
            e3 = (e3 == bk) ? 0u : e3;
            e4 = (e4 == bk) ? 0u : e4;
            e5 = (e5 == bk) ? 0u : e5;
            if (laneid == 0) cand[q][r] = 4095u - (bk & 4095u);
        }
    }
    __syncthreads();

    // ---- exact f32 rerank of 32 candidates per query (Round-1 arithmetic) ----
    int rq = t >> 4, rs = t & 15;
    float qxx = xxb[n0 + rq];
    const float4* qr = (const float4*)qrow[rq];
    uint32_t mycol[2], mykey[2];
    #pragma unroll
    for (int e = 0; e < 2; ++e) {
        uint32_t col = cand[rq][rs + 16 * e];
        const float4* cr = (const float4*)(xtb + (size_t)col * 64);
        float a = 0.f;
        #pragma unroll
        for (int i = 0; i < 16; ++i) {
            float4 qv = qr[i], cv = cr[i];
            a = fmaf(qv.x, cv.x, a); a = fmaf(qv.y, cv.y, a);
            a = fmaf(qv.z, cv.z, a); a = fmaf(qv.w, cv.w, a);
        }
        float d = 2.f * a - qxx - xxb[col];
        mycol[e] = col;
        mykey[e] = fkey(d);
        rkk[rq][rs + 16 * e] = mykey[e];
    }
    __syncthreads();
    size_t ob = ((size_t)(b * NN) + n0 + rq) * KNN;
    #pragma unroll
    for (int e = 0; e < 2; ++e) {
        uint32_t ke = mykey[e], ce = mycol[e];
        int rank = 0;
        #pragma unroll
        for (int jj = 0; jj < 32; ++jj) {
            uint32_t kj = rkk[rq][jj], cj = cand[rq][jj];
            rank += (kj > ke || (kj == ke && cj < ce)) ? 1 : 0;
        }
        if (rank < KNN) idx[ob + rank] = (int)ce;
    }
}

// ---------------- K3a: Z = xt @ W0^T, Z2 = xt @ (W1-W0)^T ----------------
__global__ __launch_bounds__(256) void k3a_gemm(const float* __restrict__ xt,
                                                const float* __restrict__ W,
                                                float* __restrict__ Z,
                                                float* __restrict__ Z2) {
    __shared__ float W0t[64][65];
    __shared__ float W21t[64][65];
    __shared__ float xs[16][64];
    int t = threadIdx.x;
    #pragma unroll
    for (int it = 0; it < 16; ++it) {
        int i = it * 256 + t;
        int o = i >> 6, c = i & 63;
        float w0 = W[o * 128 + c];
        float w1 = W[o * 128 + 64 + c];
        W0t[c][o]  = w0;
        W21t[c][o] = w1 - w0;
    }
    int b  = blockIdx.x / (NN / 16);
    int nb = (blockIdx.x % (NN / 16)) * 16;
    #pragma unroll
    for (int it = 0; it < 4; ++it) {
        int i = it * 256 + t;
        int r = i >> 6, c = i & 63;
        xs[r][c] = xt[((size_t)(b * NN + nb + r)) * C + c];
    }
    __syncthreads();
    int o = t & 63, rg = t >> 6;
    #pragma unroll
    for (int rr = 0; rr < 4; ++rr) {
        int r = rg * 4 + rr;
        float z = 0.f, z2 = 0.f;
        #pragma unroll
        for (int c = 0; c < 64; ++c) {
            float xv = xs[r][c];
            z  = fmaf(xv, W0t[c][o],  z);
            z2 = fmaf(xv, W21t[c][o], z2);
        }
        size_t off = ((size_t)(b * NN + nb + r)) * 64 + o;
        Z[off]  = z;
        Z2[off] = z2;
    }
}

// ---------------- K3b: gather neighbors, per-(b,n,o) max/min over k, block-partial sums ----------------
__global__ __launch_bounds__(256) void k3b_gather(const float* __restrict__ Z,
                                                  const float* __restrict__ Z2,
                                                  const int* __restrict__ idx,
                                                  float* __restrict__ maxY,
                                                  float* __restrict__ minY,
                                                  float* __restrict__ partials) {
    int t = threadIdx.x;
    int p = t >> 6, o = t & 63;
    int b = blockIdx.x / (NN / 4);
    int n = (blockIdx.x % (NN / 4)) * 4 + p;
    size_t base = (size_t)(b * NN + n);
    float z2 = Z2[base * 64 + o];
    __shared__ int sidx[4][KNN];
    if (o < KNN) sidx[p][o] = idx[base * KNN + o];
    __syncthreads();
    const float* Zb = Z + (size_t)b * NN * 64;
    float s1 = 0.f, s2 = 0.f, mx = -INFINITY, mn = INFINITY;
    #pragma unroll
    for (int k = 0; k < KNN; ++k) {
        float y = Zb[(size_t)sidx[p][k] * 64 + o] + z2;
        s1 += y;
        s2 = fmaf(y, y, s2);
        mx = fmaxf(mx, y);
        mn = fminf(mn, y);
    }
    maxY[base * 64 + o] = mx;
    minY[base * 64 + o] = mn;
    __shared__ float red[2][4][64];
    red[0][p][o] = s1;
    red[1][p][o] = s2;
    __syncthreads();
    if (t < 64) {
        float a = red[0][0][t] + red[0][1][t] + red[0][2][t] + red[0][3][t];
        float c = red[1][0][t] + red[1][1][t] + red[1][2][t] + red[1][3][t];
        partials[(size_t)blockIdx.x * 128 + t]      = a;
        partials[(size_t)blockIdx.x * 128 + 64 + t] = c;
    }
}

// ---------------- K4a: reduce 8192 partial rows -> 64 rows ----------------
__global__ __launch_bounds__(256) void k4a_reduce(const float* __restrict__ partials,
                                                  float* __restrict__ partials2) {
    int g = blockIdx.x;          // 0..63
    int t = threadIdx.x;
    int col = t & 127, half = t >> 7;
    float s = 0.f;
    for (int r = half; r < 128; r += 2)
        s += partials[((size_t)g * 128 + r) * 128 + col];
    __shared__ float red[2][128];
    red[half][col] = s;
    __syncthreads();
    if (t < 128) partials2[(size_t)g * 128 + t] = red[0][t] + red[1][t];
}

// ---------------- K4b: final stats -> scale/shift per channel ----------------
__global__ __launch_bounds__(128) void k4b_stats(const float* __restrict__ partials2,
                                                 const float* __restrict__ gamma,
                                                 const float* __restrict__ beta,
                                                 float* __restrict__ ss) {
    int t = threadIdx.x;   // 0..127
    double s = 0.0;
    for (int i = 0; i < 64; ++i)
        s += (double)partials2[(size_t)i * 128 + t];
    __shared__ double red[128];
    red[t] = s;
    __syncthreads();
    if (t < 64) {
        double a = red[t], c = red[64 + t];
        double M = (double)B * NN * KNN;
        double mean = a / M;
        double var  = c / M - mean * mean;
        float sc = gamma[t] * rsqrtf((float)var + 1e-5f);
        float sh = beta[t] - (float)mean * sc;
        ss[t]      = sc;
        ss[64 + t] = sh;
    }
}

// ---------------- K5: normalize + leakyrelu + transpose to (B,O,N) ----------------
__global__ __launch_bounds__(256) void k5_out(const float* __restrict__ maxY,
                                              const float* __restrict__ minY,
                                              const float* __restrict__ ss,
                                              float* __restrict__ out) {
    __shared__ float tile[64][65];
    __shared__ float sc[64], sh[64];
    int t = threadIdx.x;
    if (t < 64) { sc[t] = ss[t]; sh[t] = ss[64 + t]; }
    int b  = blockIdx.x / (NN / 64);
    int n0 = (blockIdx.x % (NN / 64)) * 64;
    __syncthreads();
    #pragma unroll
    for (int it = 0; it < 16; ++it) {
        int i = it * 256 + t;
        int nl = i >> 6, o = i & 63;
        size_t off = ((size_t)(b * NN + n0 + nl)) * 64 + o;
        float s = sc[o];
        float v = (s >= 0.f) ? maxY[off] : minY[off];
        v = fmaf(v, s, sh[o]);
        v = (v >= 0.f) ? v : 0.2f * v;
        tile[nl][o] = v;
    }
    __syncthreads();
    #pragma unroll
    for (int it = 0; it < 16; ++it) {
        int i = it * 256 + t;
        int o = i >> 6, nl = i & 63;
        out[((size_t)(b * O + o)) * NN + n0 + nl] = tile[nl][o];
    }
}

extern "C" void kernel_launch(void* const* d_in, const int* in_sizes, int n_in,
                              void* d_out, int out_size, void* d_ws, size_t ws_size,
                              hipStream_t stream) {
    const float* x     = (const float*)d_in[0];
    const float* W     = (const float*)d_in[1];
    const float* gamma = (const float*)d_in[2];
    const float* beta  = (const float*)d_in[3];
    float* out = (float*)d_out;

    float* ws = (float*)d_ws;
    float* xx = ws;                                                // B*N
    float* xt = xx + (size_t)B * NN;                               // B*N*C f32
    __hip_bfloat16* xh = (__hip_bfloat16*)(xt + (size_t)B * NN * C); // B*N*C bf16
    int*   idx = (int*)(xh + (size_t)B * NN * C);                  // B*N*KNN ints
    float* Z   = (float*)(idx + (size_t)B * NN * KNN);             // B*N*O
    float* Z2  = Z + (size_t)B * NN * O;
    float* maxY = Z2 + (size_t)B * NN * O;
    float* minY = maxY + (size_t)B * NN * O;
    float* partials  = minY + (size_t)B * NN * O;                  // (B*N/4)*128
    float* partials2 = partials + (size_t)(B * NN / 4) * 128;      // 64*128
    float* ss = partials2 + 64 * 128;                              // 128

    k1_split<<<B * (NN / 64), 256, 0, stream>>>(x, xt, xh, xx);
    k2_knn<<<B * (NN / 16), 256, 0, stream>>>(xh, xt, xx, idx);
    k3a_gemm<<<B * (NN / 16), 256, 0, stream>>>(xt, W, Z, Z2);
    k3b_gather<<<B * (NN / 4), 256, 0, stream>>>(Z, Z2, idx, maxY, minY, partials);
    k4a_reduce<<<64, 256, 0, stream>>>(partials, partials2);
    k4b_stats<<<1, 128, 0, stream>>>(partials2, gamma, beta, ss);
    k5_out<<<B * (NN / 64), 256, 0, stream>>>(maxY, minY, ss, out);
}

// Round 7
// 270.265 us; speedup vs baseline: 11.1706x; 1.1380x over previous
//
#include <hip/hip_runtime.h>
#include <hip/hip_bf16.h>
#include <math.h>

#define B 8
#define C 64
#define NN 4096
#define O 64
#define KNN 20

typedef float f32x4 __attribute__((ext_vector_type(4)));
typedef short short8_t __attribute__((ext_vector_type(8)));

__device__ inline uint32_t fkey(float f) {
    uint32_t u = __float_as_uint(f);
    return u ^ (((uint32_t)((int32_t)u >> 31)) | 0x80000000u);
}

__device__ inline uint32_t med3u(uint32_t a, uint32_t b, uint32_t c) {
    uint32_t r;
    asm("v_med3_u32 %0, %1, %2, %3" : "=v"(r) : "v"(a), "v"(b), "v"(c));
    return r;
}
__device__ inline uint32_t umax(uint32_t a, uint32_t b) { return a > b ? a : b; }

// max-reduce over each 16-lane group, result in ALL 16 lanes. Pure VALU (DPP),
// no LDS pipe. Sequence row_mirror -> row_half_mirror -> qperm(xor2) -> qperm(xor1)
// doubles coverage each step to all 16 lanes.
__device__ inline uint32_t maxall16(uint32_t v) {
    uint32_t t;
    t = (uint32_t)__builtin_amdgcn_update_dpp(0, (int)v, 0x140, 0xF, 0xF, true); // row_mirror
    v = umax(v, t);
    t = (uint32_t)__builtin_amdgcn_update_dpp(0, (int)v, 0x141, 0xF, 0xF, true); // row_half_mirror
    v = umax(v, t);
    t = (uint32_t)__builtin_amdgcn_update_dpp(0, (int)v, 0x4E, 0xF, 0xF, true);  // quad_perm [2,3,0,1]
    v = umax(v, t);
    t = (uint32_t)__builtin_amdgcn_update_dpp(0, (int)v, 0xB1, 0xF, 0xF, true);  // quad_perm [1,0,3,2]
    v = umax(v, t);
    return v;
}

// ---------------- K1: x (B,C,N) -> xt f32 (B,N,C) + xh bf16 (B,N,C), xx = sum_c x^2 ----------------
__global__ __launch_bounds__(256) void k1_split(const float* __restrict__ x,
                                                float* __restrict__ xt,
                                                __hip_bfloat16* __restrict__ xh,
                                                float* __restrict__ xx) {
    __shared__ float tile[64][65];
    int b  = blockIdx.x / (NN / 64);
    int n0 = (blockIdx.x % (NN / 64)) * 64;
    int t = threadIdx.x;
    #pragma unroll
    for (int it = 0; it < 16; ++it) {
        int i = it * 256 + t;
        int c = i >> 6, n = i & 63;
        tile[c][n] = x[(size_t)b * C * NN + (size_t)c * NN + n0 + n];
    }
    __syncthreads();
    #pragma unroll
    for (int it = 0; it < 16; ++it) {
        int i = it * 256 + t;
        int n = i >> 6, c = i & 63;
        float v = tile[c][n];
        size_t off = ((size_t)(b * NN + n0 + n)) * C + c;
        xt[off] = v;
        xh[off] = __float2bfloat16(v);
    }
    if (t < 64) {
        float s = 0.f;
        #pragma unroll
        for (int c = 0; c < 64; ++c) { float v = tile[c][t]; s = fmaf(v, v, s); }
        xx[(size_t)b * NN + t + n0] = s;
    }
}

// ---------------- K2: bf16-MFMA approx filter (packed keys, med3 queues, DPP tournaments) ----------------
// block = 256 threads (4 waves), 16 queries/block. Wave w owns candidate strip
// [w*1024,(w+1)*1024) in 64 MFMA tiles of 16 cols. Per-lane sorted top-12 queue
// per query; packed entry = (approx_key & 0xFFFFF000) | (4095-col). Wave top-24
// by DPP tournament; block merge 96->32; exact f32 rerank (Round-1 arithmetic).
__global__ __launch_bounds__(256) void k2_knn(const __hip_bfloat16* __restrict__ xh,
                                              const float* __restrict__ xt,
                                              const float* __restrict__ xx,
                                              int* __restrict__ idx) {
    int b  = blockIdx.x >> 8;
    int n0 = (blockIdx.x & 255) << 4;
    int t = threadIdx.x;
    int w = t >> 6, lane = t & 63;
    int laneid = lane & 15, grp = lane >> 4;

    const __hip_bfloat16* xhb = xh + (size_t)b * NN * 64;
    const float* xxb = xx + (size_t)b * NN;
    const float* xtb = xt + (size_t)b * NN * 64;

    // A fragments: row = query n0+laneid, k = grp*8 .. grp*8+7 (and +32)
    size_t qoff = (size_t)(n0 + laneid) * 64 + grp * 8;
    short8_t Ah0 = *(const short8_t*)(xhb + qoff);
    short8_t Ah1 = *(const short8_t*)(xhb + qoff + 32);

    // per-lane sorted queues (desc), packed u32 entries
    uint32_t qq[4][12];
    #pragma unroll
    for (int j = 0; j < 4; ++j)
        #pragma unroll
        for (int i = 0; i < 12; ++i) qq[j][i] = 0;

    #pragma unroll 1
    for (int c = 0; c < 4; ++c) {
        int cbase = w * 1024 + c * 256;
        #pragma unroll
        for (int tl = 0; tl < 16; ++tl) {
            int cand_i = cbase + tl * 16 + laneid;
            size_t coff = (size_t)cand_i * 64 + grp * 8;
            short8_t Bh0 = *(const short8_t*)(xhb + coff);
            short8_t Bh1 = *(const short8_t*)(xhb + coff + 32);
            f32x4 acc = {0.f, 0.f, 0.f, 0.f};
            acc = __builtin_amdgcn_mfma_f32_16x16x32_bf16(Ah0, Bh0, acc, 0, 0, 0);
            acc = __builtin_amdgcn_mfma_f32_16x16x32_bf16(Ah1, Bh1, acc, 0, 0, 0);
            float xxc = xxb[cand_i];
            uint32_t invcol = 4095u - (uint32_t)cand_i;
            #pragma unroll
            for (int j = 0; j < 4; ++j) {
                uint32_t nv = (fkey(fmaf(acc[j], 2.f, -xxc)) & 0xFFFFF000u) | invcol;
                // sorted insert: all slots read OLD values -> independent med3 ops
                #pragma unroll
                for (int i = 11; i >= 1; --i)
                    qq[j][i] = med3u(qq[j][i - 1], qq[j][i], nv);
                qq[j][0] = umax(qq[j][0], nv);
            }
        }
    }

    __shared__ uint32_t mbuf[16][4][24];   // [query][wave][slot] = packed
    __shared__ uint32_t cand[16][32];      // approx top-32 cols per query
    __shared__ uint32_t rkk[16][32];       // exact f32 keys
    __shared__ float qrow[16][64];         // f32 query rows

    // stage f32 query rows
    #pragma unroll
    for (int i = 0; i < 4; ++i) {
        int e = i * 256 + t;
        int r = e >> 6, cc = e & 63;
        qrow[r][cc] = xtb[(size_t)(n0 + r) * 64 + cc];
    }

    // ---- wave top-24 extraction: DPP tournament over 16 queue heads ----
    #pragma unroll 1
    for (int r = 0; r < 24; ++r) {
        #pragma unroll
        for (int j = 0; j < 4; ++j) {
            uint32_t bk = maxall16(qq[j][0]);
            bool win = (qq[j][0] == bk);   // packed values unique -> single winner
            #pragma unroll
            for (int i = 0; i < 11; ++i) qq[j][i] = win ? qq[j][i + 1] : qq[j][i];
            qq[j][11] = win ? 0u : qq[j][11];
            if (laneid == 0) mbuf[grp * 4 + j][w][r] = bk;
        }
    }
    __syncthreads();

    // ---- merge 96 -> approx top-32 per query ----
    {
        int q = w * 4 + grp;
        const uint32_t* mb = &mbuf[q][0][0];
        uint32_t e0 = mb[laneid],      e1 = mb[16 + laneid], e2 = mb[32 + laneid],
                 e3 = mb[48 + laneid], e4 = mb[64 + laneid], e5 = mb[80 + laneid];
        #pragma unroll 1
        for (int r = 0; r < 32; ++r) {
            uint32_t bk = umax(umax(umax(e0, e1), umax(e2, e3)), umax(e4, e5));
            bk = maxall16(bk);
            e0 = (e0 == bk) ? 0u : e0;
            e1 = (e1 == bk) ? 0u : e1;
            e2 = (e2 == bk) ? 0u : e2;
            e3 = (e3 == bk) ? 0u : e3;
            e4 = (e4 == bk) ? 0u : e4;
            e5 = (e5 == bk) ? 0u : e5;
            if (laneid == 0) cand[q][r] = 4095u - (bk & 4095u);
        }
    }
    __syncthreads();

    // ---- exact f32 rerank of 32 candidates per query (Round-1 arithmetic) ----
    int rq = t >> 4, rs = t & 15;
    float qxx = xxb[n0 + rq];
    const float4* qr = (const float4*)qrow[rq];
    uint32_t mycol[2], mykey[2];
    #pragma unroll
    for (int e = 0; e < 2; ++e) {
        uint32_t col = cand[rq][rs + 16 * e];
        const float4* cr = (const float4*)(xtb + (size_t)col * 64);
        float a = 0.f;
        #pragma unroll
        for (int i = 0; i < 16; ++i) {
            float4 qv = qr[i], cv = cr[i];
            a = fmaf(qv.x, cv.x, a); a = fmaf(qv.y, cv.y, a);
            a = fmaf(qv.z, cv.z, a); a = fmaf(qv.w, cv.w, a);
        }
        float d = 2.f * a - qxx - xxb[col];
        mycol[e] = col;
        mykey[e] = fkey(d);
        rkk[rq][rs + 16 * e] = mykey[e];
    }
    __syncthreads();
    size_t ob = ((size_t)(b * NN) + n0 + rq) * KNN;
    #pragma unroll
    for (int e = 0; e < 2; ++e) {
        uint32_t ke = mykey[e], ce = mycol[e];
        int rank = 0;
        #pragma unroll
        for (int jj = 0; jj < 32; ++jj) {
            uint32_t kj = rkk[rq][jj], cj = cand[rq][jj];
            rank += (kj > ke || (kj == ke && cj < ce)) ? 1 : 0;
        }
        if (rank < KNN) idx[ob + rank] = (int)ce;
    }
}

// ---------------- K3a: Z = xt @ W0^T, Z2 = xt @ (W1-W0)^T ----------------
__global__ __launch_bounds__(256) void k3a_gemm(const float* __restrict__ xt,
                                                const float* __restrict__ W,
                                                float* __restrict__ Z,
                                                float* __restrict__ Z2) {
    __shared__ float W0t[64][65];
    __shared__ float W21t[64][65];
    __shared__ float xs[16][64];
    int t = threadIdx.x;
    #pragma unroll
    for (int it = 0; it < 16; ++it) {
        int i = it * 256 + t;
        int o = i >> 6, c = i & 63;
        float w0 = W[o * 128 + c];
        float w1 = W[o * 128 + 64 + c];
        W0t[c][o]  = w0;
        W21t[c][o] = w1 - w0;
    }
    int b  = blockIdx.x / (NN / 16);
    int nb = (blockIdx.x % (NN / 16)) * 16;
    #pragma unroll
    for (int it = 0; it < 4; ++it) {
        int i = it * 256 + t;
        int r = i >> 6, c = i & 63;
        xs[r][c] = xt[((size_t)(b * NN + nb + r)) * C + c];
    }
    __syncthreads();
    int o = t & 63, rg = t >> 6;
    #pragma unroll
    for (int rr = 0; rr < 4; ++rr) {
        int r = rg * 4 + rr;
        float z = 0.f, z2 = 0.f;
        #pragma unroll
        for (int c = 0; c < 64; ++c) {
            float xv = xs[r][c];
            z  = fmaf(xv, W0t[c][o],  z);
            z2 = fmaf(xv, W21t[c][o], z2);
        }
        size_t off = ((size_t)(b * NN + nb + r)) * 64 + o;
        Z[off]  = z;
        Z2[off] = z2;
    }
}

// ---------------- K3b: gather neighbors, per-(b,n,o) max/min over k, block-partial sums ----------------
__global__ __launch_bounds__(256) void k3b_gather(const float* __restrict__ Z,
                                                  const float* __restrict__ Z2,
                                                  const int* __restrict__ idx,
                                                  float* __restrict__ maxY,
                                                  float* __restrict__ minY,
                                                  float* __restrict__ partials) {
    int t = threadIdx.x;
    int p = t >> 6, o = t & 63;
    int b = blockIdx.x / (NN / 4);
    int n = (blockIdx.x % (NN / 4)) * 4 + p;
    size_t base = (size_t)(b * NN + n);
    float z2 = Z2[base * 64 + o];
    __shared__ int sidx[4][KNN];
    if (o < KNN) sidx[p][o] = idx[base * KNN + o];
    __syncthreads();
    const float* Zb = Z + (size_t)b * NN * 64;
    float s1 = 0.f, s2 = 0.f, mx = -INFINITY, mn = INFINITY;
    #pragma unroll
    for (int k = 0; k < KNN; ++k) {
        float y = Zb[(size_t)sidx[p][k] * 64 + o] + z2;
        s1 += y;
        s2 = fmaf(y, y, s2);
        mx = fmaxf(mx, y);
        mn = fminf(mn, y);
    }
    maxY[base * 64 + o] = mx;
    minY[base * 64 + o] = mn;
    __shared__ float red[2][4][64];
    red[0][p][o] = s1;
    red[1][p][o] = s2;
    __syncthreads();
    if (t < 64) {
        float a = red[0][0][t] + red[0][1][t] + red[0][2][t] + red[0][3][t];
        float c = red[1][0][t] + red[1][1][t] + red[1][2][t] + red[1][3][t];
        partials[(size_t)blockIdx.x * 128 + t]      = a;
        partials[(size_t)blockIdx.x * 128 + 64 + t] = c;
    }
}

// ---------------- K4a: reduce 8192 partial rows -> 64 rows ----------------
__global__ __launch_bounds__(256) void k4a_reduce(const float* __restrict__ partials,
                                                  float* __restrict__ partials2) {
    int g = blockIdx.x;          // 0..63
    int t = threadIdx.x;
    int col = t & 127, half = t >> 7;
    float s = 0.f;
    for (int r = half; r < 128; r += 2)
        s += partials[((size_t)g * 128 + r) * 128 + col];
    __shared__ float red[2][128];
    red[half][col] = s;
    __syncthreads();
    if (t < 128) partials2[(size_t)g * 128 + t] = red[0][t] + red[1][t];
}

// ---------------- K4b: final stats -> scale/shift per channel ----------------
__global__ __launch_bounds__(128) void k4b_stats(const float* __restrict__ partials2,
                                                 const float* __restrict__ gamma,
                                                 const float* __restrict__ beta,
                                                 float* __restrict__ ss) {
    int t = threadIdx.x;   // 0..127
    double s = 0.0;
    for (int i = 0; i < 64; ++i)
        s += (double)partials2[(size_t)i * 128 + t];
    __shared__ double red[128];
    red[t] = s;
    __syncthreads();
    if (t < 64) {
        double a = red[t], c = red[64 + t];
        double M = (double)B * NN * KNN;
        double mean = a / M;
        double var  = c / M - mean * mean;
        float sc = gamma[t] * rsqrtf((float)var + 1e-5f);
        float sh = beta[t] - (float)mean * sc;
        ss[t]      = sc;
        ss[64 + t] = sh;
    }
}

// ---------------- K5: normalize + leakyrelu + transpose to (B,O,N) ----------------
__global__ __launch_bounds__(256) void k5_out(const float* __restrict__ maxY,
                                              const float* __restrict__ minY,
                                              const float* __restrict__ ss,
                                              float* __restrict__ out) {
    __shared__ float tile[64][65];
    __shared__ float sc[64], sh[64];
    int t = threadIdx.x;
    if (t < 64) { sc[t] = ss[t]; sh[t] = ss[64 + t]; }
    int b  = blockIdx.x / (NN / 64);
    int n0 = (blockIdx.x % (NN / 64)) * 64;
    __syncthreads();
    #pragma unroll
    for (int it = 0; it < 16; ++it) {
        int i = it * 256 + t;
        int nl = i >> 6, o = i & 63;
        size_t off = ((size_t)(b * NN + n0 + nl)) * 64 + o;
        float s = sc[o];
        float v = (s >= 0.f) ? maxY[off] : minY[off];
        v = fmaf(v, s, sh[o]);
        v = (v >= 0.f) ? v : 0.2f * v;
        tile[nl][o] = v;
    }
    __syncthreads();
    #pragma unroll
    for (int it = 0; it < 16; ++it) {
        int i = it * 256 + t;
        int o = i >> 6, nl = i & 63;
        out[((size_t)(b * O + o)) * NN + n0 + nl] = tile[nl][o];
    }
}

extern "C" void kernel_launch(void* const* d_in, const int* in_sizes, int n_in,
                              void* d_out, int out_size, void* d_ws, size_t ws_size,
                              hipStream_t stream) {
    const float* x     = (const float*)d_in[0];
    const float* W     = (const float*)d_in[1];
    const float* gamma = (const float*)d_in[2];
    const float* beta  = (const float*)d_in[3];
    float* out = (float*)d_out;

    float* ws = (float*)d_ws;
    float* xx = ws;                                                // B*N
    float* xt = xx + (size_t)B * NN;                               // B*N*C f32
    __hip_bfloat16* xh = (__hip_bfloat16*)(xt + (size_t)B * NN * C); // B*N*C bf16
    int*   idx = (int*)(xh + (size_t)B * NN * C);                  // B*N*KNN ints
    float* Z   = (float*)(idx + (size_t)B * NN * KNN);             // B*N*O
    float* Z2  = Z + (size_t)B * NN * O;
    float* maxY = Z2 + (size_t)B * NN * O;
    float* minY = maxY + (size_t)B * NN * O;
    float* partials  = minY + (size_t)B * NN * O;                  // (B*N/4)*128
    float* partials2 = partials + (size_t)(B * NN / 4) * 128;      // 64*128
    float* ss = partials2 + 64 * 128;                              // 128

    k1_split<<<B * (NN / 64), 256, 0, stream>>>(x, xt, xh, xx);
    k2_knn<<<B * (NN / 16), 256, 0, stream>>>(xh, xt, xx, idx);
    k3a_gemm<<<B * (NN / 16), 256, 0, stream>>>(xt, W, Z, Z2);
    k3b_gather<<<B * (NN / 4), 256, 0, stream>>>(Z, Z2, idx, maxY, minY, partials);
    k4a_reduce<<<64, 256, 0, stream>>>(partials, partials2);
    k4b_stats<<<1, 128, 0, stream>>>(partials2, gamma, beta, ss);
    k5_out<<<B * (NN / 64), 256, 0, stream>>>(maxY, minY, ss, out);
}

// Round 8
// 254.050 us; speedup vs baseline: 11.8836x; 1.0638x over previous
//
#include <hip/hip_runtime.h>
#include <hip/hip_bf16.h>
#include <math.h>

#define B 8
#define C 64
#define NN 4096
#define O 64
#define KNN 20

typedef float f32x4 __attribute__((ext_vector_type(4)));
typedef short short8_t __attribute__((ext_vector_type(8)));

__device__ inline uint32_t fkey(float f) {
    uint32_t u = __float_as_uint(f);
    return u ^ (((uint32_t)((int32_t)u >> 31)) | 0x80000000u);
}

__device__ inline uint32_t med3u(uint32_t a, uint32_t b, uint32_t c) {
    uint32_t r;
    asm("v_med3_u32 %0, %1, %2, %3" : "=v"(r) : "v"(a), "v"(b), "v"(c));
    return r;
}
__device__ inline uint32_t umax(uint32_t a, uint32_t b) { return a > b ? a : b; }

// max-reduce over each 16-lane group, result in ALL 16 lanes. Pure VALU (DPP).
__device__ inline uint32_t maxall16(uint32_t v) {
    uint32_t t;
    t = (uint32_t)__builtin_amdgcn_update_dpp(0, (int)v, 0x140, 0xF, 0xF, true); // row_mirror
    v = umax(v, t);
    t = (uint32_t)__builtin_amdgcn_update_dpp(0, (int)v, 0x141, 0xF, 0xF, true); // row_half_mirror
    v = umax(v, t);
    t = (uint32_t)__builtin_amdgcn_update_dpp(0, (int)v, 0x4E, 0xF, 0xF, true);  // quad_perm [2,3,0,1]
    v = umax(v, t);
    t = (uint32_t)__builtin_amdgcn_update_dpp(0, (int)v, 0xB1, 0xF, 0xF, true);  // quad_perm [1,0,3,2]
    v = umax(v, t);
    return v;
}

// ---------------- K1: x (B,C,N) -> xt f32 (B,N,C) + xh bf16 (B,N,C), xx = sum_c x^2 ----------------
__global__ __launch_bounds__(256) void k1_split(const float* __restrict__ x,
                                                float* __restrict__ xt,
                                                __hip_bfloat16* __restrict__ xh,
                                                float* __restrict__ xx) {
    __shared__ float tile[64][65];
    int b  = blockIdx.x / (NN / 64);
    int n0 = (blockIdx.x % (NN / 64)) * 64;
    int t = threadIdx.x;
    #pragma unroll
    for (int it = 0; it < 16; ++it) {
        int i = it * 256 + t;
        int c = i >> 6, n = i & 63;
        tile[c][n] = x[(size_t)b * C * NN + (size_t)c * NN + n0 + n];
    }
    __syncthreads();
    #pragma unroll
    for (int it = 0; it < 16; ++it) {
        int i = it * 256 + t;
        int n = i >> 6, c = i & 63;
        float v = tile[c][n];
        size_t off = ((size_t)(b * NN + n0 + n)) * C + c;
        xt[off] = v;
        xh[off] = __float2bfloat16(v);
    }
    if (t < 64) {
        float s = 0.f;
        #pragma unroll
        for (int c = 0; c < 64; ++c) { float v = tile[c][t]; s = fmaf(v, v, s); }
        xx[(size_t)b * NN + t + n0] = s;
    }
}

// ---------------- K2: bf16-MFMA approx filter -> per-lane queues -> top-32 -> exact f32 rerank ----------------
// XCD swizzle: b = blockIdx&7 so (assuming round-robin block->XCD dispatch) each
// XCD's L2 holds only ITS batch's xh (512KB) + xt (1MB) + xx.
// Wave w owns candidate strip [w*1024,(w+1)*1024) in 64 MFMA tiles of 16 cols,
// with explicit next-tile prefetch. Per-lane sorted top-12 queue per query;
// packed entry = (approx_key & 0xFFFFF000) | (4095-col). Wave top-20 by DPP
// tournament; block merge 80->32; exact f32 rerank (Round-1 arithmetic).
__global__ __launch_bounds__(256) void k2_knn(const __hip_bfloat16* __restrict__ xh,
                                              const float* __restrict__ xt,
                                              const float* __restrict__ xx,
                                              int* __restrict__ idx) {
    int b  = blockIdx.x & 7;
    int n0 = (blockIdx.x >> 3) << 4;
    int t = threadIdx.x;
    int w = t >> 6, lane = t & 63;
    int laneid = lane & 15, grp = lane >> 4;

    const __hip_bfloat16* xhb = xh + (size_t)b * NN * 64;
    const float* xxb = xx + (size_t)b * NN;
    const float* xtb = xt + (size_t)b * NN * 64;

    // A fragments: row = query n0+laneid, k = grp*8 .. grp*8+7 (and +32)
    size_t qoff = (size_t)(n0 + laneid) * 64 + grp * 8;
    short8_t Ah0 = *(const short8_t*)(xhb + qoff);
    short8_t Ah1 = *(const short8_t*)(xhb + qoff + 32);

    // per-lane sorted queues (desc), packed u32 entries
    uint32_t qq[4][12];
    #pragma unroll
    for (int j = 0; j < 4; ++j)
        #pragma unroll
        for (int i = 0; i < 12; ++i) qq[j][i] = 0;

    // ---- sweep: 64 tiles with 2-deep prefetch ----
    int cand0 = w * 1024 + laneid;
    {
        const __hip_bfloat16* p0 = xhb + (size_t)cand0 * 64 + grp * 8;
        short8_t nB0 = *(const short8_t*)p0;
        short8_t nB1 = *(const short8_t*)(p0 + 32);
        float nxx = xxb[cand0];
        #pragma unroll 4
        for (int tt = 0; tt < 64; ++tt) {
            short8_t B0 = nB0, B1 = nB1;
            float xxc = nxx;
            int ci = cand0 + tt * 16;
            // prefetch next tile. For tt==63 this over-reads <=2KB past this
            // batch's xh/xx rows into the adjacent workspace arrays — allocated
            // memory, values never used.
            {
                const __hip_bfloat16* np = xhb + (size_t)(ci + 16) * 64 + grp * 8;
                nB0 = *(const short8_t*)np;
                nB1 = *(const short8_t*)(np + 32);
                nxx = xxb[ci + 16];
            }
            f32x4 acc = {0.f, 0.f, 0.f, 0.f};
            acc = __builtin_amdgcn_mfma_f32_16x16x32_bf16(Ah0, B0, acc, 0, 0, 0);
            acc = __builtin_amdgcn_mfma_f32_16x16x32_bf16(Ah1, B1, acc, 0, 0, 0);
            uint32_t invcol = 4095u - (uint32_t)ci;
            #pragma unroll
            for (int j = 0; j < 4; ++j) {
                uint32_t nv = (fkey(fmaf(acc[j], 2.f, -xxc)) & 0xFFFFF000u) | invcol;
                // sorted insert: all slots read OLD values -> independent med3 ops
                #pragma unroll
                for (int i = 11; i >= 1; --i)
                    qq[j][i] = med3u(qq[j][i - 1], qq[j][i], nv);
                qq[j][0] = umax(qq[j][0], nv);
            }
        }
    }

    __shared__ uint32_t mbuf[16][4][20];   // [query][wave][slot] = packed
    __shared__ uint32_t cand[16][32];      // approx top-32 cols per query
    __shared__ uint32_t rkk[16][32];       // exact f32 keys
    __shared__ float qrow[16][64];         // f32 query rows

    // stage f32 query rows
    #pragma unroll
    for (int i = 0; i < 4; ++i) {
        int e = i * 256 + t;
        int r = e >> 6, cc = e & 63;
        qrow[r][cc] = xtb[(size_t)(n0 + r) * 64 + cc];
    }

    // ---- wave top-20 extraction: DPP tournament over 16 queue heads ----
    #pragma unroll 1
    for (int r = 0; r < 20; ++r) {
        #pragma unroll
        for (int j = 0; j < 4; ++j) {
            uint32_t bk = maxall16(qq[j][0]);
            bool win = (qq[j][0] == bk);   // packed values unique -> single winner
            #pragma unroll
            for (int i = 0; i < 11; ++i) qq[j][i] = win ? qq[j][i + 1] : qq[j][i];
            qq[j][11] = win ? 0u : qq[j][11];
            if (laneid == 0) mbuf[grp * 4 + j][w][r] = bk;
        }
    }
    __syncthreads();

    // ---- merge 80 -> approx top-32 per query ----
    {
        int q = w * 4 + grp;
        const uint32_t* mb = &mbuf[q][0][0];
        uint32_t e0 = mb[laneid],      e1 = mb[16 + laneid], e2 = mb[32 + laneid],
                 e3 = mb[48 + laneid], e4 = mb[64 + laneid];
        #pragma unroll 1
        for (int r = 0; r < 32; ++r) {
            uint32_t bk = umax(umax(umax(e0, e1), umax(e2, e3)), e4);
            bk = maxall16(bk);
            e0 = (e0 == bk) ? 0u : e0;
            e1 = (e1 == bk) ? 0u : e1;
            e2 = (e2 == bk) ? 0u : e2;
            e3 = (e3 == bk) ? 0u : e3;
            e4 = (e4 == bk) ? 0u : e4;
            if (laneid == 0) cand[q][r] = 4095u - (bk & 4095u);
        }
    }
    __syncthreads();

    // ---- exact f32 rerank of 32 candidates per query (Round-1 arithmetic) ----
    int rq = t >> 4, rs = t & 15;
    float qxx = xxb[n0 + rq];
    const float4* qr = (const float4*)qrow[rq];
    uint32_t mycol[2], mykey[2];
    #pragma unroll
    for (int e = 0; e < 2; ++e) {
        uint32_t col = cand[rq][rs + 16 * e];
        const float4* cr = (const float4*)(xtb + (size_t)col * 64);
        float a = 0.f;
        #pragma unroll
        for (int i = 0; i < 16; ++i) {
            float4 qv = qr[i], cv = cr[i];
            a = fmaf(qv.x, cv.x, a); a = fmaf(qv.y, cv.y, a);
            a = fmaf(qv.z, cv.z, a); a = fmaf(qv.w, cv.w, a);
        }
        float d = 2.f * a - qxx - xxb[col];
        mycol[e] = col;
        mykey[e] = fkey(d);
        rkk[rq][rs + 16 * e] = mykey[e];
    }
    __syncthreads();
    size_t ob = ((size_t)(b * NN) + n0 + rq) * KNN;
    #pragma unroll
    for (int e = 0; e < 2; ++e) {
        uint32_t ke = mykey[e], ce = mycol[e];
        int rank = 0;
        #pragma unroll
        for (int jj = 0; jj < 32; ++jj) {
            uint32_t kj = rkk[rq][jj], cj = cand[rq][jj];
            rank += (kj > ke || (kj == ke && cj < ce)) ? 1 : 0;
        }
        if (rank < KNN) idx[ob + rank] = (int)ce;
    }
}

// ---------------- K3a: Z = xt @ W0^T, Z2 = xt @ (W1-W0)^T ----------------
__global__ __launch_bounds__(256) void k3a_gemm(const float* __restrict__ xt,
                                                const float* __restrict__ W,
                                                float* __restrict__ Z,
                                                float* __restrict__ Z2) {
    __shared__ float W0t[64][65];
    __shared__ float W21t[64][65];
    __shared__ float xs[16][64];
    int t = threadIdx.x;
    #pragma unroll
    for (int it = 0; it < 16; ++it) {
        int i = it * 256 + t;
        int o = i >> 6, c = i & 63;
        float w0 = W[o * 128 + c];
        float w1 = W[o * 128 + 64 + c];
        W0t[c][o]  = w0;
        W21t[c][o] = w1 - w0;
    }
    int b  = blockIdx.x / (NN / 16);
    int nb = (blockIdx.x % (NN / 16)) * 16;
    #pragma unroll
    for (int it = 0; it < 4; ++it) {
        int i = it * 256 + t;
        int r = i >> 6, c = i & 63;
        xs[r][c] = xt[((size_t)(b * NN + nb + r)) * C + c];
    }
    __syncthreads();
    int o = t & 63, rg = t >> 6;
    #pragma unroll
    for (int rr = 0; rr < 4; ++rr) {
        int r = rg * 4 + rr;
        float z = 0.f, z2 = 0.f;
        #pragma unroll
        for (int c = 0; c < 64; ++c) {
            float xv = xs[r][c];
            z  = fmaf(xv, W0t[c][o],  z);
            z2 = fmaf(xv, W21t[c][o], z2);
        }
        size_t off = ((size_t)(b * NN + nb + r)) * 64 + o;
        Z[off]  = z;
        Z2[off] = z2;
    }
}

// ---------------- K3b: gather neighbors, per-(b,n,o) max/min over k, block-partial sums ----------------
// XCD swizzle: b = blockIdx&7 pins each batch's Z/Z2 (2MB) to one XCD's L2.
__global__ __launch_bounds__(256) void k3b_gather(const float* __restrict__ Z,
                                                  const float* __restrict__ Z2,
                                                  const int* __restrict__ idx,
                                                  float* __restrict__ maxY,
                                                  float* __restrict__ minY,
                                                  float* __restrict__ partials) {
    int t = threadIdx.x;
    int p = t >> 6, o = t & 63;
    int b = blockIdx.x & 7;
    int n = (blockIdx.x >> 3) * 4 + p;
    size_t base = (size_t)(b * NN + n);
    float z2 = Z2[base * 64 + o];
    __shared__ int sidx[4][KNN];
    if (o < KNN) sidx[p][o] = idx[base * KNN + o];
    __syncthreads();
    const float* Zb = Z + (size_t)b * NN * 64;
    float s1 = 0.f, s2 = 0.f, mx = -INFINITY, mn = INFINITY;
    #pragma unroll
    for (int k = 0; k < KNN; ++k) {
        float y = Zb[(size_t)sidx[p][k] * 64 + o] + z2;
        s1 += y;
        s2 = fmaf(y, y, s2);
        mx = fmaxf(mx, y);
        mn = fminf(mn, y);
    }
    maxY[base * 64 + o] = mx;
    minY[base * 64 + o] = mn;
    __shared__ float red[2][4][64];
    red[0][p][o] = s1;
    red[1][p][o] = s2;
    __syncthreads();
    if (t < 64) {
        float a = red[0][0][t] + red[0][1][t] + red[0][2][t] + red[0][3][t];
        float c = red[1][0][t] + red[1][1][t] + red[1][2][t] + red[1][3][t];
        partials[(size_t)blockIdx.x * 128 + t]      = a;
        partials[(size_t)blockIdx.x * 128 + 64 + t] = c;
    }
}

// ---------------- K4a: reduce 8192 partial rows -> 64 rows ----------------
__global__ __launch_bounds__(256) void k4a_reduce(const float* __restrict__ partials,
                                                  float* __restrict__ partials2) {
    int g = blockIdx.x;          // 0..63
    int t = threadIdx.x;
    int col = t & 127, half = t >> 7;
    float s = 0.f;
    for (int r = half; r < 128; r += 2)
        s += partials[((size_t)g * 128 + r) * 128 + col];
    __shared__ float red[2][128];
    red[half][col] = s;
    __syncthreads();
    if (t < 128) partials2[(size_t)g * 128 + t] = red[0][t] + red[1][t];
}

// ---------------- K4b: final stats -> scale/shift per channel ----------------
__global__ __launch_bounds__(128) void k4b_stats(const float* __restrict__ partials2,
                                                 const float* __restrict__ gamma,
                                                 const float* __restrict__ beta,
                                                 float* __restrict__ ss) {
    int t = threadIdx.x;   // 0..127
    double s = 0.0;
    for (int i = 0; i < 64; ++i)
        s += (double)partials2[(size_t)i * 128 + t];
    __shared__ double red[128];
    red[t] = s;
    __syncthreads();
    if (t < 64) {
        double a = red[t], c = red[64 + t];
        double M = (double)B * NN * KNN;
        double mean = a / M;
        double var  = c / M - mean * mean;
        float sc = gamma[t] * rsqrtf((float)var + 1e-5f);
        float sh = beta[t] - (float)mean * sc;
        ss[t]      = sc;
        ss[64 + t] = sh;
    }
}

// ---------------- K5: normalize + leakyrelu + transpose to (B,O,N) ----------------
__global__ __launch_bounds__(256) void k5_out(const float* __restrict__ maxY,
                                              const float* __restrict__ minY,
                                              const float* __restrict__ ss,
                                              float* __restrict__ out) {
    __shared__ float tile[64][65];
    __shared__ float sc[64], sh[64];
    int t = threadIdx.x;
    if (t < 64) { sc[t] = ss[t]; sh[t] = ss[64 + t]; }
    int b  = blockIdx.x / (NN / 64);
    int n0 = (blockIdx.x % (NN / 64)) * 64;
    __syncthreads();
    #pragma unroll
    for (int it = 0; it < 16; ++it) {
        int i = it * 256 + t;
        int nl = i >> 6, o = i & 63;
        size_t off = ((size_t)(b * NN + n0 + nl)) * 64 + o;
        float s = sc[o];
        float v = (s >= 0.f) ? maxY[off] : minY[off];
        v = fmaf(v, s, sh[o]);
        v = (v >= 0.f) ? v : 0.2f * v;
        tile[nl][o] = v;
    }
    __syncthreads();
    #pragma unroll
    for (int it = 0; it < 16; ++it) {
        int i = it * 256 + t;
        int o = i >> 6, nl = i & 63;
        out[((size_t)(b * O + o)) * NN + n0 + nl] = tile[nl][o];
    }
}

extern "C" void kernel_launch(void* const* d_in, const int* in_sizes, int n_in,
                              void* d_out, int out_size, void* d_ws, size_t ws_size,
                              hipStream_t stream) {
    const float* x     = (const float*)d_in[0];
    const float* W     = (const float*)d_in[1];
    const float* gamma = (const float*)d_in[2];
    const float* beta  = (const float*)d_in[3];
    float* out = (float*)d_out;

    float* ws = (float*)d_ws;
    float* xx = ws;                                                // B*N
    float* xt = xx + (size_t)B * NN;                               // B*N*C f32
    __hip_bfloat16* xh = (__hip_bfloat16*)(xt + (size_t)B * NN * C); // B*N*C bf16
    int*   idx = (int*)(xh + (size_t)B * NN * C);                  // B*N*KNN ints
    float* Z   = (float*)(idx + (size_t)B * NN * KNN);             // B*N*O
    float* Z2  = Z + (size_t)B * NN * O;
    float* maxY = Z2 + (size_t)B * NN * O;
    float* minY = maxY + (size_t)B * NN * O;
    float* partials  = minY + (size_t)B * NN * O;                  // (B*N/4)*128
    float* partials2 = partials + (size_t)(B * NN / 4) * 128;      // 64*128
    float* ss = partials2 + 64 * 128;                              // 128

    k1_split<<<B * (NN / 64), 256, 0, stream>>>(x, xt, xh, xx);
    k2_knn<<<B * (NN / 16), 256, 0, stream>>>(xh, xt, xx, idx);
    k3a_gemm<<<B * (NN / 16), 256, 0, stream>>>(xt, W, Z, Z2);
    k3b_gather<<<B * (NN / 4), 256, 0, stream>>>(Z, Z2, idx, maxY, minY, partials);
    k4a_reduce<<<64, 256, 0, stream>>>(partials, partials2);
    k4b_stats<<<1, 128, 0, stream>>>(partials2, gamma, beta, ss);
    k5_out<<<B * (NN / 64), 256, 0, stream>>>(maxY, minY, ss, out);
}